// Round 6
// baseline (168.358 us; speedup 1.0000x reference)
//
#include <hip/hip_runtime.h>
#include <math.h>

#define NN 256
#define FEAT 1024
#define HIDR 256
#define GCNH 256
#define M1 1024            // HEADS*GCNH
#define OUTC 21
#define MAXDEG (NN + 1)    // up to 256 topk-incoming + 1 self loop
#define KC 4               // split-K factor (was 16: P volume -> 6.3 MB)
#define KCH (FEAT / KC)    // 256
#define RB 16              // rows per k_big block
#define FCOLS 1536         // fused output cols: A(256) | B(256) | hpre(1024)

// ---------------------------------------------------------------------------
// Write-through (agent-scope relaxed atomic) stores — ONLY for the small
// cross-barrier buffers inside k_fused (~1.3 MB total). The P tensor uses
// regular cached stores (WT on P was round-4's regression).
__device__ __forceinline__ void st_wt4(float* p, float4 v) {
    union { float4 f; unsigned long long u[2]; } cv; cv.f = v;
    __hip_atomic_store((unsigned long long*)p, cv.u[0],
                       __ATOMIC_RELAXED, __HIP_MEMORY_SCOPE_AGENT);
    __hip_atomic_store((unsigned long long*)p + 1, cv.u[1],
                       __ATOMIC_RELAXED, __HIP_MEMORY_SCOPE_AGENT);
}
__device__ __forceinline__ void st_wtf(float* p, float v) {
    __hip_atomic_store((unsigned*)p, __float_as_uint(v),
                       __ATOMIC_RELAXED, __HIP_MEMORY_SCOPE_AGENT);
}
__device__ __forceinline__ void st_wti(int* p, int v) {
    __hip_atomic_store(p, v, __ATOMIC_RELAXED, __HIP_MEMORY_SCOPE_AGENT);
}

// ---------------------------------------------------------------------------
// K1: fused split-K GEMM (round-2 structure: LDS-staged feat, register
// double-buffered weights, regular cached stores). KC=4: same inner loop,
// 4x longer K-chunk per block — P round-trip shrinks 25 -> 6.3 MB while
// total FLOPs/weight traffic are unchanged. Compute per 4-k prefetch step
// (16 rows x 4 k x 2 cols = 128 fma = 256 cyc/SIMD) covers L2 latency.
// grid (16 row-groups, 3 col-groups of 512, 4 K-chunks) = 192 blocks.
__global__ __launch_bounds__(256) void k_big(
        const float* __restrict__ feat, const float* __restrict__ Wfc1,
        const float* __restrict__ W1, float* __restrict__ P,
        unsigned* bar) {
    if (blockIdx.x == 0 && blockIdx.y == 0 && blockIdx.z == 0 &&
        threadIdx.x == 0)
        __hip_atomic_store(bar, 0u, __ATOMIC_RELAXED, __HIP_MEMORY_SCOPE_AGENT);
    __shared__ float fS[RB][KCH];
    int rg = blockIdx.x, cgy = blockIdx.y, kc = blockIdx.z;
    int tid = threadIdx.x;
    int r0 = rg * RB, k0 = kc * KCH;
    for (int x = tid; x < RB * KCH; x += 256) {
        int r = x / KCH, kk = x & (KCH - 1);
        fS[r][kk] = feat[(size_t)(r0 + r) * FEAT + k0 + kk];
    }
    __syncthreads();
    int gc = cgy * 512 + tid * 2;
    const float* pW;
    int ld;
    if (gc < 256)      { pW = Wfc1 + (size_t)k0 * HIDR + gc;                  ld = HIDR; }
    else if (gc < 512) { pW = Wfc1 + (size_t)(FEAT + k0) * HIDR + (gc - 256); ld = HIDR; }
    else               { pW = W1   + (size_t)k0 * M1 + (gc - 512);            ld = M1;   }
    float2 acc[RB];
#pragma unroll
    for (int r = 0; r < RB; r++) { acc[r].x = 0.f; acc[r].y = 0.f; }
    float2 w0 = *(const float2*)(pW);
    float2 w1 = *(const float2*)(pW + ld);
    float2 w2 = *(const float2*)(pW + 2 * ld);
    float2 w3 = *(const float2*)(pW + 3 * ld);
    for (int kk = 0; kk < KCH; kk += 4) {
        pW += 4 * ld;
        // one-group overshoot bounds (kc=3, k0=768): A-region reads Wfc1
        // rows <=1027 (<2052), B-region <=2051 (=last row), W1 <=1027
        // (<1028) — all in-bounds.
        float2 n0 = *(const float2*)(pW);
        float2 n1 = *(const float2*)(pW + ld);
        float2 n2 = *(const float2*)(pW + 2 * ld);
        float2 n3 = *(const float2*)(pW + 3 * ld);
#pragma unroll
        for (int r = 0; r < RB; r++) {
            float4 f = *(const float4*)&fS[r][kk];
            acc[r].x = fmaf(f.x, w0.x, acc[r].x); acc[r].y = fmaf(f.x, w0.y, acc[r].y);
            acc[r].x = fmaf(f.y, w1.x, acc[r].x); acc[r].y = fmaf(f.y, w1.y, acc[r].y);
            acc[r].x = fmaf(f.z, w2.x, acc[r].x); acc[r].y = fmaf(f.z, w2.y, acc[r].y);
            acc[r].x = fmaf(f.w, w3.x, acc[r].x); acc[r].y = fmaf(f.w, w3.y, acc[r].y);
        }
        w0 = n0; w1 = n1; w2 = n2; w3 = n3;
    }
    // P layout: [row][kc][col] -> stage-A reads one 24KB contiguous span/row.
    float* Pp = P + ((size_t)r0 * KC + kc) * FCOLS + gc;
#pragma unroll
    for (int r = 0; r < RB; r++)
        *(float2*)(Pp + (size_t)r * KC * FCOLS) = acc[r];
}

// ---------------------------------------------------------------------------
// Grid barrier: relaxed arrive + relaxed spin. NO agent-scope acquire:
// every cross-block buffer is WT-stored and never read before its barrier
// within this launch, so no XCD can hold a stale line. Workgroup acquire =
// compile-time ordering + L1 only.
__device__ __forceinline__ void gsync(unsigned* bar, unsigned expected) {
    __syncthreads();   // drains vmcnt: all WT stores at device-coherent point
    if (threadIdx.x == 0) {
        __hip_atomic_fetch_add(bar, 1u, __ATOMIC_RELAXED,
                               __HIP_MEMORY_SCOPE_AGENT);
        while (__hip_atomic_load(bar, __ATOMIC_RELAXED,
                                 __HIP_MEMORY_SCOPE_AGENT) < expected)
            __builtin_amdgcn_s_sleep(1);
    }
    __syncthreads();
    __builtin_amdgcn_fence(__ATOMIC_ACQUIRE, "workgroup");
}

// ---------------------------------------------------------------------------
// K2: 4 stages, 3 grid barriers. grid 256 (row/target), block 512.
//  A: split-K reduce (4 partials) + route + geom fixup + es1/ed1 dots
//  B: fused rel-row + top-3 (weights via uniform scalar-path loads, no LDS)
//  C: ballot edge build + GAT-1 softmax/aggregate + h2 + es2/ed2 dots
//  D: GAT-2 softmax-aggregate -> logits + argmax labels
__global__ __launch_bounds__(512, 4) void k_fused(
        const float* __restrict__ P, const float* __restrict__ bfc1,
        const float* __restrict__ boxes, const int* __restrict__ imh,
        const int* __restrict__ imw, const float* __restrict__ W1,
        const float* __restrict__ as1, const float* __restrict__ ad1,
        const float* __restrict__ Wfc1, const float* __restrict__ Wfc2,
        const float* __restrict__ b1, const float* __restrict__ W2,
        const float* __restrict__ as2, const float* __restrict__ ad2,
        const float* __restrict__ b2,
        float* __restrict__ A, float* __restrict__ BT4,
        float* __restrict__ hpre, float* __restrict__ es1,
        float* __restrict__ ed1, int* __restrict__ idxTop,
        float* __restrict__ h2, float* __restrict__ es2,
        float* __restrict__ ed2, unsigned* bar, float* __restrict__ out) {
    __shared__ float gS[4];
    __shared__ float sval[512];
    __shared__ unsigned long long swk[8];
    __shared__ int win;
    __shared__ int pfxw[4];
    __shared__ int lst[MAXDEG];
    __shared__ int dgS;
    __shared__ float sc[MAXDEG * 4];
    __shared__ float sh[M1];
    __shared__ float part[24 * OUTC];
    __shared__ float h2row[OUTC];
    __shared__ float scD[MAXDEG];
    __shared__ float lv[OUTC];

    int row = blockIdx.x, tid = threadIdx.x;

    // ===== stage A: reduce 4 split-K partials + route + fixup =============
    int c4 = tid * 4;
    bool actA = (tid < 384);
    float4 s4;
    if (actA) {
        const float* p = P + (size_t)row * (KC * FCOLS) + c4;
        float4 a0 = *(const float4*)(p);
        float4 a1 = *(const float4*)(p + FCOLS);
        float4 a2 = *(const float4*)(p + 2 * FCOLS);
        float4 a3 = *(const float4*)(p + 3 * FCOLS);
        s4.x = (a0.x + a1.x) + (a2.x + a3.x);
        s4.y = (a0.y + a1.y) + (a2.y + a3.y);
        s4.z = (a0.z + a1.z) + (a2.z + a3.z);
        s4.w = (a0.w + a1.w) + (a2.w + a3.w);
    }
    if (tid == 0) {
        float w = (float)imw[0], h = (float)imh[0];
        float x1 = boxes[row * 4 + 0] / w, y1 = boxes[row * 4 + 1] / h;
        float x2 = boxes[row * 4 + 2] / w, y2 = boxes[row * 4 + 3] / h;
        gS[0] = x1; gS[1] = y1; gS[2] = x2 - x1; gS[3] = y2 - y1;
    }
    __syncthreads();
    if (actA) {
        if (c4 < 256) {
            float4 bv = *(const float4*)(bfc1 + c4);
            s4.x += bv.x; s4.y += bv.y; s4.z += bv.z; s4.w += bv.w;
            st_wt4(A + (size_t)row * HIDR + c4, s4);
        } else if (c4 < 512) {
            int kk = c4 - 256;
            st_wt4(BT4 + (size_t)(kk >> 2) * (NN * 4) + row * 4, s4);
        } else {
            int ch = c4 - 512;
            float g0 = gS[0], g1 = gS[1], g2 = gS[2], g3 = gS[3];
            float4 wv;
            wv = *(const float4*)(W1 + (size_t)(FEAT + 0) * M1 + ch);
            s4.x = fmaf(g0, wv.x, s4.x); s4.y = fmaf(g0, wv.y, s4.y);
            s4.z = fmaf(g0, wv.z, s4.z); s4.w = fmaf(g0, wv.w, s4.w);
            wv = *(const float4*)(W1 + (size_t)(FEAT + 1) * M1 + ch);
            s4.x = fmaf(g1, wv.x, s4.x); s4.y = fmaf(g1, wv.y, s4.y);
            s4.z = fmaf(g1, wv.z, s4.z); s4.w = fmaf(g1, wv.w, s4.w);
            wv = *(const float4*)(W1 + (size_t)(FEAT + 2) * M1 + ch);
            s4.x = fmaf(g2, wv.x, s4.x); s4.y = fmaf(g2, wv.y, s4.y);
            s4.z = fmaf(g2, wv.z, s4.z); s4.w = fmaf(g2, wv.w, s4.w);
            wv = *(const float4*)(W1 + (size_t)(FEAT + 3) * M1 + ch);
            s4.x = fmaf(g3, wv.x, s4.x); s4.y = fmaf(g3, wv.y, s4.y);
            s4.z = fmaf(g3, wv.z, s4.z); s4.w = fmaf(g3, wv.w, s4.w);
            st_wt4(hpre + (size_t)row * M1 + ch, s4);
            float4 a = *(const float4*)(as1 + ch);
            float4 bv = *(const float4*)(ad1 + ch);
            float ps = s4.x * a.x + s4.y * a.y + s4.z * a.z + s4.w * a.w;
            float pd = s4.x * bv.x + s4.y * bv.y + s4.z * bv.z + s4.w * bv.w;
#pragma unroll
            for (int o = 32; o > 0; o >>= 1) {
                ps += __shfl_down(ps, o);
                pd += __shfl_down(pd, o);
            }
            if ((tid & 63) == 0) {
                int head = (tid - 128) >> 6;
                st_wtf(es1 + row * 4 + head, ps);
                st_wtf(ed1 + row * 4 + head, pd);
            }
        }
    }
    // hoist stage-B box geometry (input-only) above the barrier wait
    int j = tid & 255;
    float bi0 = boxes[row * 4 + 0], bi1 = boxes[row * 4 + 1];
    float bi2 = boxes[row * 4 + 2], bi3 = boxes[row * 4 + 3];
    float g0 = fabsf(bi0 - boxes[j * 4 + 0]);
    float g1 = fabsf(bi1 - boxes[j * 4 + 1]);
    float g2 = fabsf(bi2 - boxes[j * 4 + 2]);
    float g3 = fabsf(bi3 - boxes[j * 4 + 3]);

    gsync(bar, NN);          // A/BT4/hpre/es1/ed1 visible grid-wide

    // ===== stage B: fused rel-row + top-3 (no LDS staging) ================
    {
        int half = __builtin_amdgcn_readfirstlane(tid >> 8);  // wave-uniform
        int k0 = half * 128;
        const float* pB  = BT4 + (size_t)(k0 >> 2) * (NN * 4) + j * 4;
        const float* pA  = A + (size_t)row * HIDR + k0;
        const float* pW2 = Wfc2 + k0;
        const float* pg0 = Wfc1 + (size_t)(2 * FEAT + 0) * HIDR + k0;
        const float* pg1 = Wfc1 + (size_t)(2 * FEAT + 1) * HIDR + k0;
        const float* pg2 = Wfc1 + (size_t)(2 * FEAT + 2) * HIDR + k0;
        const float* pg3 = Wfc1 + (size_t)(2 * FEAT + 3) * HIDR + k0;
        float acc = 0.f;
#pragma unroll 4
        for (int kk = 0; kk < 128; kk += 4) {
            float4 a4 = *(const float4*)(pA + kk);    // uniform (broadcast)
            float4 w4 = *(const float4*)(pW2 + kk);   // uniform -> s_load
            float4 q0 = *(const float4*)(pg0 + kk);
            float4 q1 = *(const float4*)(pg1 + kk);
            float4 q2 = *(const float4*)(pg2 + kk);
            float4 q3 = *(const float4*)(pg3 + kk);
            float4 b4 = *(const float4*)pB;
            pB += NN * 4;
            float v;
            v = a4.x + b4.x; v = fmaf(g0, q0.x, v); v = fmaf(g1, q1.x, v);
            v = fmaf(g2, q2.x, v); v = fmaf(g3, q3.x, v);
            acc = fmaf(fmaxf(v, 0.f), w4.x, acc);
            v = a4.y + b4.y; v = fmaf(g0, q0.y, v); v = fmaf(g1, q1.y, v);
            v = fmaf(g2, q2.y, v); v = fmaf(g3, q3.y, v);
            acc = fmaf(fmaxf(v, 0.f), w4.y, acc);
            v = a4.z + b4.z; v = fmaf(g0, q0.z, v); v = fmaf(g1, q1.z, v);
            v = fmaf(g2, q2.z, v); v = fmaf(g3, q3.z, v);
            acc = fmaf(fmaxf(v, 0.f), w4.z, acc);
            v = a4.w + b4.w; v = fmaf(g0, q0.w, v); v = fmaf(g1, q1.w, v);
            v = fmaf(g2, q2.w, v); v = fmaf(g3, q3.w, v);
            acc = fmaf(fmaxf(v, 0.f), w4.w, acc);
        }
        sval[tid] = acc;
    }
    __syncthreads();
    if (tid < 256) sval[tid] = sval[tid] + sval[tid + 256];
    __syncthreads();
    for (int r = 0; r < 4; r++) {
        unsigned long long key = 0ULL;
        if (tid < 256) {
            unsigned u = __float_as_uint(sval[tid]);
            u = (u & 0x80000000u) ? ~u : (u | 0x80000000u);
            key = ((unsigned long long)u << 32) | (unsigned)(NN - 1 - tid);
        }
#pragma unroll
        for (int o = 32; o > 0; o >>= 1) {
            unsigned long long nk = __shfl_down(key, o);
            if (nk > key) key = nk;
        }
        if ((tid & 63) == 0) swk[tid >> 6] = key;
        __syncthreads();
        if (tid == 0) {
            unsigned long long m = swk[0];
#pragma unroll
            for (int q = 1; q < 8; q++) if (swk[q] > m) m = swk[q];
            int wj = NN - 1 - (int)(m & 0xFFFFFFFFu);
            win = wj;
            if (r > 0) st_wti(idxTop + row * 3 + (r - 1), wj);
        }
        __syncthreads();
        if (tid == win) sval[tid] = -1e38f;
        __syncthreads();
    }

    gsync(bar, 2 * NN);      // idxTop visible grid-wide

    // ===== stage C: edge-list (ballot scan) + GAT-1 + h2 + es2/ed2 ========
    int f = 0;
    if (tid < 256)
        f = (idxTop[tid * 3 + 0] == row) | (idxTop[tid * 3 + 1] == row)
          | (idxTop[tid * 3 + 2] == row);
    unsigned long long bm = __ballot(f);
    int lane = tid & 63, wv6 = tid >> 6;
    int rank = __popcll(bm & ((1ULL << lane) - 1ULL));
    if (tid < 256 && lane == 0) pfxw[wv6] = __popcll(bm);
    __syncthreads();
    {
        int base = 0;
#pragma unroll
        for (int w = 0; w < 4; w++) base += (w < wv6) ? pfxw[w] : 0;
        if (tid < 256 && f) lst[base + rank] = tid;
    }
    if (tid == 0) {
        int tot = pfxw[0] + pfxw[1] + pfxw[2] + pfxw[3];
        lst[tot] = row;                   // GATConv self loop
        dgS = tot + 1;
    }
    __syncthreads();
    int dg = dgS;
    for (int p = tid; p < dg * 4; p += 512) {
        int e = p >> 2, hq2 = p & 3;
        int s = lst[e];
        float v = es1[s * 4 + hq2] + ed1[row * 4 + hq2];
        sc[p] = v >= 0.f ? v : 0.2f * v;  // leaky_relu(0.2)
    }
    __syncthreads();
    int hq = tid & 3;
    {
        float lm = -1e30f;
        for (int e = tid >> 2; e < dg; e += 128)
            lm = fmaxf(lm, sc[e * 4 + hq]);
#pragma unroll
        for (int o = 4; o <= 32; o <<= 1) lm = fmaxf(lm, __shfl_xor(lm, o));
        if (lane < 4) sval[wv6 * 4 + hq] = lm;
        __syncthreads();
        float m = sval[hq];
#pragma unroll
        for (int w = 1; w < 8; w++) m = fmaxf(m, sval[w * 4 + hq]);
        float ls = 0.f;
        for (int e = tid >> 2; e < dg; e += 128) {
            float pv = expf(sc[e * 4 + hq] - m);
            sc[e * 4 + hq] = pv;
            ls += pv;
        }
#pragma unroll
        for (int o = 4; o <= 32; o <<= 1) ls += __shfl_xor(ls, o);
        if (lane < 4) sval[32 + wv6 * 4 + hq] = ls;
        __syncthreads();
        float den = sval[32 + hq];
#pragma unroll
        for (int w = 1; w < 8; w++) den += sval[32 + w * 4 + hq];
        for (int e = tid >> 2; e < dg; e += 128)
            sc[e * 4 + hq] = sc[e * 4 + hq] / den;   // alpha
    }
    __syncthreads();
    {
        int col = tid & 255, hh = (tid >> 8) * 2;   // heads {hh, hh+1}
        float acc0 = 0.f, acc1 = 0.f;
        int e = 0;
        for (; e + 8 <= dg; e += 8) {
            float v0[8], v1[8];
#pragma unroll
            for (int u = 0; u < 8; u++) {
                const float* hs = hpre + (size_t)lst[e + u] * M1;
                v0[u] = hs[hh * GCNH + col];
                v1[u] = hs[(hh + 1) * GCNH + col];
            }
#pragma unroll
            for (int u = 0; u < 8; u++) {
                acc0 = fmaf(sc[(e + u) * 4 + hh],     v0[u], acc0);
                acc1 = fmaf(sc[(e + u) * 4 + hh + 1], v1[u], acc1);
            }
        }
        for (; e < dg; e++) {
            const float* hs = hpre + (size_t)lst[e] * M1;
            acc0 = fmaf(sc[e * 4 + hh],     hs[hh * GCNH + col],       acc0);
            acc1 = fmaf(sc[e * 4 + hh + 1], hs[(hh + 1) * GCNH + col], acc1);
        }
        int c0 = hh * GCNH + col, c1 = (hh + 1) * GCNH + col;
        sh[c0] = fmaxf(acc0 + b1[c0], 0.f);
        sh[c1] = fmaxf(acc1 + b1[c1], 0.f);
    }
    __syncthreads();
    if (tid < 504) {                      // 24-way split of 1024 -> 21
        int o = tid % OUTC, pq = tid / OUTC;
        float a2 = 0.f;
        for (int d = pq; d < M1; d += 24)
            a2 = fmaf(sh[d], W2[d * OUTC + o], a2);
        part[pq * OUTC + o] = a2;
    }
    __syncthreads();
    if (tid < OUTC) {
        float ssum = 0.f;
        for (int pq = 0; pq < 24; pq++) ssum += part[pq * OUTC + tid];
        st_wtf(h2 + row * OUTC + tid, ssum);
        h2row[tid] = ssum;
    }
    __syncthreads();
    if (tid == 0) {
        float ssum = 0.f, dd = 0.f;
        for (int k = 0; k < OUTC; k++) {
            ssum = fmaf(h2row[k], as2[k], ssum);
            dd = fmaf(h2row[k], ad2[k], dd);
        }
        st_wtf(es2 + row, ssum);
        st_wtf(ed2 + row, dd);
    }

    gsync(bar, 3 * NN);      // h2/es2/ed2 visible grid-wide

    // ===== stage D: GAT-2 aggregate -> logits + labels ====================
    int dgT = dgS;                        // lst/dgS persist in LDS
    float edt = ed2[row];
    for (int p = tid; p < dgT; p += 512) {
        int s = lst[p];
        float v = es2[s] + edt;
        scD[p] = v >= 0.f ? v : 0.2f * v;
    }
    __syncthreads();
    {
        float lm = -1e30f;
        for (int p = tid; p < dgT; p += 512) lm = fmaxf(lm, scD[p]);
#pragma unroll
        for (int o = 1; o <= 32; o <<= 1) lm = fmaxf(lm, __shfl_xor(lm, o));
        if (lane == 0) sval[wv6] = lm;
        __syncthreads();
        float m = sval[0];
#pragma unroll
        for (int w = 1; w < 8; w++) m = fmaxf(m, sval[w]);
        float ls = 0.f;
        for (int p = tid; p < dgT; p += 512) {
            float pv = expf(scD[p] - m);
            scD[p] = pv;
            ls += pv;
        }
#pragma unroll
        for (int o = 1; o <= 32; o <<= 1) ls += __shfl_xor(ls, o);
        if (lane == 0) sval[8 + wv6] = ls;
        __syncthreads();
        float den = sval[8];
#pragma unroll
        for (int w = 1; w < 8; w++) den += sval[8 + w];
        __syncthreads();
        if (tid < 504) {                  // (edge-group, out-channel) map
            int o = tid % OUTC, eg = tid / OUTC;
            float acc = 0.f;
            for (int e = eg; e < dgT; e += 24) {
                int s = lst[e];
                acc = fmaf(scD[e], h2[(size_t)s * OUTC + o], acc);
            }
            part[eg * OUTC + o] = acc;
        }
        __syncthreads();
        if (tid < OUTC) {
            float ssum = 0.f;
            for (int eg = 0; eg < 24; eg++) ssum += part[eg * OUTC + tid];
            float v = ssum / den + b2[tid];
            out[row * OUTC + tid] = v;
            lv[tid] = v;
        }
    }
    __syncthreads();
    if (tid == 0) {
        int best = 0;
        float bv = lv[0];
        for (int o = 1; o < OUTC; o++)
            if (lv[o] > bv) { bv = lv[o]; best = o; }  // first max wins
        out[NN * OUTC + row] = (float)best;
    }
}

// ---------------------------------------------------------------------------
extern "C" void kernel_launch(void* const* d_in, const int* in_sizes, int n_in,
                              void* d_out, int out_size, void* d_ws,
                              size_t ws_size, hipStream_t stream) {
    const float* feat  = (const float*)d_in[0];
    const float* boxes = (const float*)d_in[1];
    const float* Wfc1  = (const float*)d_in[2];
    const float* bfc1  = (const float*)d_in[3];
    const float* Wfc2  = (const float*)d_in[4];
    const float* bfc2  = (const float*)d_in[5];   (void)bfc2;
    const float* W1    = (const float*)d_in[6];
    const float* as1   = (const float*)d_in[7];
    const float* ad1   = (const float*)d_in[8];
    const float* b1    = (const float*)d_in[9];
    const float* W2    = (const float*)d_in[10];
    const float* as2   = (const float*)d_in[11];
    const float* ad2   = (const float*)d_in[12];
    const float* b2    = (const float*)d_in[13];
    const int*   imh   = (const int*)d_in[14];
    const int*   imw   = (const int*)d_in[15];

    float* ws = (float*)d_ws;
    float* P     = ws;  ws += KC * NN * FCOLS;   // 1,572,864 floats (6.3 MB)
    float* A     = ws;  ws += NN * HIDR;
    float* BT4   = ws;  ws += NN * HIDR;
    float* hpre  = ws;  ws += NN * M1;
    float* es1   = ws;  ws += NN * 4;
    float* ed1   = ws;  ws += NN * 4;
    float* h2    = ws;  ws += NN * OUTC;
    float* es2   = ws;  ws += NN;
    float* ed2   = ws;  ws += NN;
    int* idxTop  = (int*)ws;
    unsigned* bar = (unsigned*)(idxTop + NN * 3);

    float* out = (float*)d_out;

    k_big<<<dim3(NN / RB, 3, KC), 256, 0, stream>>>(feat, Wfc1, W1, P, bar);
    k_fused<<<NN, 512, 0, stream>>>(P, bfc1, boxes, imh, imw, W1, as1, ad1,
                                    Wfc1, Wfc2, b1, W2, as2, ad2, b2,
                                    A, BT4, hpre, es1, ed1, idxTop,
                                    h2, es2, ed2, bar, out);
}

// Round 7
// 150.298 us; speedup vs baseline: 1.1202x; 1.1202x over previous
//
#include <hip/hip_runtime.h>
#include <math.h>

#define NN 256
#define FEAT 1024
#define HIDR 256
#define GCNH 256
#define M1 1024            // HEADS*GCNH
#define OUTC 21
#define MAXDEG (NN + 1)    // up to 256 topk-incoming + 1 self loop
#define KC 16              // split-K factor (KC=4 regressed: round-6 post-mortem)
#define KCH (FEAT / KC)    // 64
#define RB 16              // rows per k_big block
#define FCOLS 1536         // fused output cols: A(256) | B(256) | hpre(1024)

// ---------------------------------------------------------------------------
// Write-through (agent-scope relaxed atomic) stores — ONLY for the small
// cross-barrier buffers inside k_fused (~1.3 MB total). The P tensor uses
// regular cached stores (WT on P was round-4's regression).
__device__ __forceinline__ void st_wt4(float* p, float4 v) {
    union { float4 f; unsigned long long u[2]; } cv; cv.f = v;
    __hip_atomic_store((unsigned long long*)p, cv.u[0],
                       __ATOMIC_RELAXED, __HIP_MEMORY_SCOPE_AGENT);
    __hip_atomic_store((unsigned long long*)p + 1, cv.u[1],
                       __ATOMIC_RELAXED, __HIP_MEMORY_SCOPE_AGENT);
}
__device__ __forceinline__ void st_wtf(float* p, float v) {
    __hip_atomic_store((unsigned*)p, __float_as_uint(v),
                       __ATOMIC_RELAXED, __HIP_MEMORY_SCOPE_AGENT);
}
__device__ __forceinline__ void st_wti(int* p, int v) {
    __hip_atomic_store(p, v, __ATOMIC_RELAXED, __HIP_MEMORY_SCOPE_AGENT);
}

// ---------------------------------------------------------------------------
// K1: fused split-K GEMM (round-5 structure: LDS-staged feat, register
// double-buffered weights, regular cached stores, KC=16).
// NEW: XCD-aware block swizzle. Weight chunks are indexed by (cgy,kc) only;
// without swizzle the 16 rg-blocks sharing a chunk land on all 8 XCDs and
// each XCD L2 fetches its own copy (round-6 measured: 25 MB FETCH vs ~9 MB
// unique). Mapping below puts all 16 rg-blocks of group g = cgy*16+kc on
// XCD g%8 (assumes round-robin id%8 dispatch; bijective either way):
//   id = xcd + 8*slot, g = xcd + 8*(slot/16), rg = slot%16.
// Since 16 == 0 (mod 8), the 3 cgy-groups of one kc co-locate too -> feat
// chunks dedup as well. 1-D grid of 768 blocks.
__global__ __launch_bounds__(256) void k_big(
        const float* __restrict__ feat, const float* __restrict__ Wfc1,
        const float* __restrict__ W1, float* __restrict__ P,
        unsigned* bar) {
    int id = blockIdx.x;
    if (id == 0 && threadIdx.x == 0)
        __hip_atomic_store(bar, 0u, __ATOMIC_RELAXED, __HIP_MEMORY_SCOPE_AGENT);
    int xcd = id & 7, slot = id >> 3;
    int g = xcd + 8 * (slot >> 4);       // weight group 0..47
    int rg = slot & 15;
    int cgy = g >> 4, kc = g & 15;       // g = cgy*16 + kc
    __shared__ float fS[RB][KCH];
    int tid = threadIdx.x;
    int r0 = rg * RB, k0 = kc * KCH;
    for (int x = tid; x < RB * KCH; x += 256) {
        int r = x >> 6, kk = x & (KCH - 1);
        fS[r][kk] = feat[(size_t)(r0 + r) * FEAT + k0 + kk];
    }
    __syncthreads();
    int gc = cgy * 512 + tid * 2;
    const float* pW;
    int ld;
    if (gc < 256)      { pW = Wfc1 + (size_t)k0 * HIDR + gc;                  ld = HIDR; }
    else if (gc < 512) { pW = Wfc1 + (size_t)(FEAT + k0) * HIDR + (gc - 256); ld = HIDR; }
    else               { pW = W1   + (size_t)k0 * M1 + (gc - 512);            ld = M1;   }
    float2 acc[RB];
#pragma unroll
    for (int r = 0; r < RB; r++) { acc[r].x = 0.f; acc[r].y = 0.f; }
    float2 w0 = *(const float2*)(pW);
    float2 w1 = *(const float2*)(pW + ld);
    float2 w2 = *(const float2*)(pW + 2 * ld);
    float2 w3 = *(const float2*)(pW + 3 * ld);
    for (int kk = 0; kk < KCH; kk += 4) {
        pW += 4 * ld;
        // one-group overshoot bounds: A-region reads Wfc1 rows <=1027
        // (<2052), B-region <=2051 (=last), W1 <=1027 (<1028) — in-bounds.
        float2 n0 = *(const float2*)(pW);
        float2 n1 = *(const float2*)(pW + ld);
        float2 n2 = *(const float2*)(pW + 2 * ld);
        float2 n3 = *(const float2*)(pW + 3 * ld);
#pragma unroll
        for (int r = 0; r < RB; r++) {
            float4 f = *(const float4*)&fS[r][kk];
            acc[r].x = fmaf(f.x, w0.x, acc[r].x); acc[r].y = fmaf(f.x, w0.y, acc[r].y);
            acc[r].x = fmaf(f.y, w1.x, acc[r].x); acc[r].y = fmaf(f.y, w1.y, acc[r].y);
            acc[r].x = fmaf(f.z, w2.x, acc[r].x); acc[r].y = fmaf(f.z, w2.y, acc[r].y);
            acc[r].x = fmaf(f.w, w3.x, acc[r].x); acc[r].y = fmaf(f.w, w3.y, acc[r].y);
        }
        w0 = n0; w1 = n1; w2 = n2; w3 = n3;
    }
    // P layout: [row][kc][col] -> stage-A reads one 98KB contiguous span/row.
    float* Pp = P + ((size_t)r0 * KC + kc) * FCOLS + gc;
#pragma unroll
    for (int r = 0; r < RB; r++)
        *(float2*)(Pp + (size_t)r * KC * FCOLS) = acc[r];
}

// ---------------------------------------------------------------------------
// Grid barrier: relaxed arrive + relaxed spin. NO agent-scope acquire:
// every cross-block buffer is WT-stored and never read before its barrier
// within this launch, so no XCD can hold a stale line. Workgroup acquire =
// compile-time ordering + L1 only.
__device__ __forceinline__ void gsync(unsigned* bar, unsigned expected) {
    __syncthreads();   // drains vmcnt: all WT stores at device-coherent point
    if (threadIdx.x == 0) {
        __hip_atomic_fetch_add(bar, 1u, __ATOMIC_RELAXED,
                               __HIP_MEMORY_SCOPE_AGENT);
        while (__hip_atomic_load(bar, __ATOMIC_RELAXED,
                                 __HIP_MEMORY_SCOPE_AGENT) < expected)
            __builtin_amdgcn_s_sleep(1);
    }
    __syncthreads();
    __builtin_amdgcn_fence(__ATOMIC_ACQUIRE, "workgroup");
}

// ---------------------------------------------------------------------------
// K2: 4 stages, 3 grid barriers. grid 256 (row/target), block 512.
//  A: split-K reduce + route + geom fixup + es1/ed1 dots.
//     NEW: A row kept in LDS only (was: WT-store + post-barrier L3 read —
//     pure round-trip, A[row] is produced and consumed by the same block).
//  B: fused rel-row + top-3 (weights via uniform scalar-path loads)
//  C: ballot edge build + GAT-1 softmax/aggregate + h2 + es2/ed2 dots
//  D: GAT-2 softmax-aggregate -> logits + argmax labels
__global__ __launch_bounds__(512, 4) void k_fused(
        const float* __restrict__ P, const float* __restrict__ bfc1,
        const float* __restrict__ boxes, const int* __restrict__ imh,
        const int* __restrict__ imw, const float* __restrict__ W1,
        const float* __restrict__ as1, const float* __restrict__ ad1,
        const float* __restrict__ Wfc1, const float* __restrict__ Wfc2,
        const float* __restrict__ b1, const float* __restrict__ W2,
        const float* __restrict__ as2, const float* __restrict__ ad2,
        const float* __restrict__ b2,
        float* __restrict__ BT4, float* __restrict__ hpre,
        float* __restrict__ es1, float* __restrict__ ed1,
        int* __restrict__ idxTop, float* __restrict__ h2,
        float* __restrict__ es2, float* __restrict__ ed2,
        unsigned* bar, float* __restrict__ out) {
    __shared__ float gS[4];
    __shared__ float As[HIDR];
    __shared__ float sval[512];
    __shared__ unsigned long long swk[8];
    __shared__ int win;
    __shared__ int pfxw[4];
    __shared__ int lst[MAXDEG];
    __shared__ int dgS;
    __shared__ float sc[MAXDEG * 4];
    __shared__ float sh[M1];
    __shared__ float part[24 * OUTC];
    __shared__ float h2row[OUTC];
    __shared__ float scD[MAXDEG];
    __shared__ float lv[OUTC];

    int row = blockIdx.x, tid = threadIdx.x;

    // ===== stage A: reduce 16 split-K partials + route + fixup ============
    int c4 = tid * 4;
    bool actA = (tid < 384);
    float4 s4;
    if (actA) {
        const float* p = P + (size_t)row * (KC * FCOLS) + c4;
        float4 a0 = *(const float4*)(p);
        float4 a1 = *(const float4*)(p + FCOLS);
        float4 a2 = *(const float4*)(p + 2 * FCOLS);
        float4 a3 = *(const float4*)(p + 3 * FCOLS);
#pragma unroll
        for (int q = 4; q < KC; q += 4) {
            float4 t0 = *(const float4*)(p + (size_t)q * FCOLS);
            float4 t1 = *(const float4*)(p + (size_t)(q + 1) * FCOLS);
            float4 t2 = *(const float4*)(p + (size_t)(q + 2) * FCOLS);
            float4 t3 = *(const float4*)(p + (size_t)(q + 3) * FCOLS);
            a0.x += t0.x; a0.y += t0.y; a0.z += t0.z; a0.w += t0.w;
            a1.x += t1.x; a1.y += t1.y; a1.z += t1.z; a1.w += t1.w;
            a2.x += t2.x; a2.y += t2.y; a2.z += t2.z; a2.w += t2.w;
            a3.x += t3.x; a3.y += t3.y; a3.z += t3.z; a3.w += t3.w;
        }
        s4.x = (a0.x + a1.x) + (a2.x + a3.x);
        s4.y = (a0.y + a1.y) + (a2.y + a3.y);
        s4.z = (a0.z + a1.z) + (a2.z + a3.z);
        s4.w = (a0.w + a1.w) + (a2.w + a3.w);
    }
    if (tid == 0) {
        float w = (float)imw[0], h = (float)imh[0];
        float x1 = boxes[row * 4 + 0] / w, y1 = boxes[row * 4 + 1] / h;
        float x2 = boxes[row * 4 + 2] / w, y2 = boxes[row * 4 + 3] / h;
        gS[0] = x1; gS[1] = y1; gS[2] = x2 - x1; gS[3] = y2 - y1;
    }
    __syncthreads();
    if (actA) {
        if (c4 < 256) {
            float4 bv = *(const float4*)(bfc1 + c4);
            s4.x += bv.x; s4.y += bv.y; s4.z += bv.z; s4.w += bv.w;
            *(float4*)(&As[c4]) = s4;        // LDS only — same-block consumer
        } else if (c4 < 512) {
            int kk = c4 - 256;
            st_wt4(BT4 + (size_t)(kk >> 2) * (NN * 4) + row * 4, s4);
        } else {
            int ch = c4 - 512;
            float g0 = gS[0], g1 = gS[1], g2 = gS[2], g3 = gS[3];
            float4 wv;
            wv = *(const float4*)(W1 + (size_t)(FEAT + 0) * M1 + ch);
            s4.x = fmaf(g0, wv.x, s4.x); s4.y = fmaf(g0, wv.y, s4.y);
            s4.z = fmaf(g0, wv.z, s4.z); s4.w = fmaf(g0, wv.w, s4.w);
            wv = *(const float4*)(W1 + (size_t)(FEAT + 1) * M1 + ch);
            s4.x = fmaf(g1, wv.x, s4.x); s4.y = fmaf(g1, wv.y, s4.y);
            s4.z = fmaf(g1, wv.z, s4.z); s4.w = fmaf(g1, wv.w, s4.w);
            wv = *(const float4*)(W1 + (size_t)(FEAT + 2) * M1 + ch);
            s4.x = fmaf(g2, wv.x, s4.x); s4.y = fmaf(g2, wv.y, s4.y);
            s4.z = fmaf(g2, wv.z, s4.z); s4.w = fmaf(g2, wv.w, s4.w);
            wv = *(const float4*)(W1 + (size_t)(FEAT + 3) * M1 + ch);
            s4.x = fmaf(g3, wv.x, s4.x); s4.y = fmaf(g3, wv.y, s4.y);
            s4.z = fmaf(g3, wv.z, s4.z); s4.w = fmaf(g3, wv.w, s4.w);
            st_wt4(hpre + (size_t)row * M1 + ch, s4);
            float4 a = *(const float4*)(as1 + ch);
            float4 bv = *(const float4*)(ad1 + ch);
            float ps = s4.x * a.x + s4.y * a.y + s4.z * a.z + s4.w * a.w;
            float pd = s4.x * bv.x + s4.y * bv.y + s4.z * bv.z + s4.w * bv.w;
#pragma unroll
            for (int o = 32; o > 0; o >>= 1) {
                ps += __shfl_down(ps, o);
                pd += __shfl_down(pd, o);
            }
            if ((tid & 63) == 0) {
                int head = (tid - 128) >> 6;
                st_wtf(es1 + row * 4 + head, ps);
                st_wtf(ed1 + row * 4 + head, pd);
            }
        }
    }
    // hoist stage-B box geometry (input-only) above the barrier wait
    int j = tid & 255;
    float bi0 = boxes[row * 4 + 0], bi1 = boxes[row * 4 + 1];
    float bi2 = boxes[row * 4 + 2], bi3 = boxes[row * 4 + 3];
    float g0 = fabsf(bi0 - boxes[j * 4 + 0]);
    float g1 = fabsf(bi1 - boxes[j * 4 + 1]);
    float g2 = fabsf(bi2 - boxes[j * 4 + 2]);
    float g3 = fabsf(bi3 - boxes[j * 4 + 3]);

    gsync(bar, NN);          // BT4/hpre/es1/ed1 visible grid-wide

    // ===== stage B: fused rel-row + top-3 =================================
    {
        int half = __builtin_amdgcn_readfirstlane(tid >> 8);  // wave-uniform
        int k0 = half * 128;
        const float* pB  = BT4 + (size_t)(k0 >> 2) * (NN * 4) + j * 4;
        const float* pA  = As + k0;                 // LDS broadcast
        const float* pW2 = Wfc2 + k0;
        const float* pg0 = Wfc1 + (size_t)(2 * FEAT + 0) * HIDR + k0;
        const float* pg1 = Wfc1 + (size_t)(2 * FEAT + 1) * HIDR + k0;
        const float* pg2 = Wfc1 + (size_t)(2 * FEAT + 2) * HIDR + k0;
        const float* pg3 = Wfc1 + (size_t)(2 * FEAT + 3) * HIDR + k0;
        float acc = 0.f;
#pragma unroll 4
        for (int kk = 0; kk < 128; kk += 4) {
            float4 a4 = *(const float4*)(pA + kk);    // LDS (broadcast)
            float4 w4 = *(const float4*)(pW2 + kk);   // uniform -> s_load
            float4 q0 = *(const float4*)(pg0 + kk);
            float4 q1 = *(const float4*)(pg1 + kk);
            float4 q2 = *(const float4*)(pg2 + kk);
            float4 q3 = *(const float4*)(pg3 + kk);
            float4 b4 = *(const float4*)pB;
            pB += NN * 4;
            float v;
            v = a4.x + b4.x; v = fmaf(g0, q0.x, v); v = fmaf(g1, q1.x, v);
            v = fmaf(g2, q2.x, v); v = fmaf(g3, q3.x, v);
            acc = fmaf(fmaxf(v, 0.f), w4.x, acc);
            v = a4.y + b4.y; v = fmaf(g0, q0.y, v); v = fmaf(g1, q1.y, v);
            v = fmaf(g2, q2.y, v); v = fmaf(g3, q3.y, v);
            acc = fmaf(fmaxf(v, 0.f), w4.y, acc);
            v = a4.z + b4.z; v = fmaf(g0, q0.z, v); v = fmaf(g1, q1.z, v);
            v = fmaf(g2, q2.z, v); v = fmaf(g3, q3.z, v);
            acc = fmaf(fmaxf(v, 0.f), w4.z, acc);
            v = a4.w + b4.w; v = fmaf(g0, q0.w, v); v = fmaf(g1, q1.w, v);
            v = fmaf(g2, q2.w, v); v = fmaf(g3, q3.w, v);
            acc = fmaf(fmaxf(v, 0.f), w4.w, acc);
        }
        sval[tid] = acc;
    }
    __syncthreads();
    if (tid < 256) sval[tid] = sval[tid] + sval[tid + 256];
    __syncthreads();
    for (int r = 0; r < 4; r++) {
        unsigned long long key = 0ULL;
        if (tid < 256) {
            unsigned u = __float_as_uint(sval[tid]);
            u = (u & 0x80000000u) ? ~u : (u | 0x80000000u);
            key = ((unsigned long long)u << 32) | (unsigned)(NN - 1 - tid);
        }
#pragma unroll
        for (int o = 32; o > 0; o >>= 1) {
            unsigned long long nk = __shfl_down(key, o);
            if (nk > key) key = nk;
        }
        if ((tid & 63) == 0) swk[tid >> 6] = key;
        __syncthreads();
        if (tid == 0) {
            unsigned long long m = swk[0];
#pragma unroll
            for (int q = 1; q < 8; q++) if (swk[q] > m) m = swk[q];
            int wj = NN - 1 - (int)(m & 0xFFFFFFFFu);
            win = wj;
            if (r > 0) st_wti(idxTop + row * 3 + (r - 1), wj);
        }
        __syncthreads();
        if (tid == win) sval[tid] = -1e38f;
        __syncthreads();
    }

    gsync(bar, 2 * NN);      // idxTop visible grid-wide

    // ===== stage C: edge-list (ballot scan) + GAT-1 + h2 + es2/ed2 ========
    int f = 0;
    if (tid < 256)
        f = (idxTop[tid * 3 + 0] == row) | (idxTop[tid * 3 + 1] == row)
          | (idxTop[tid * 3 + 2] == row);
    unsigned long long bm = __ballot(f);
    int lane = tid & 63, wv6 = tid >> 6;
    int rank = __popcll(bm & ((1ULL << lane) - 1ULL));
    if (tid < 256 && lane == 0) pfxw[wv6] = __popcll(bm);
    __syncthreads();
    {
        int base = 0;
#pragma unroll
        for (int w = 0; w < 4; w++) base += (w < wv6) ? pfxw[w] : 0;
        if (tid < 256 && f) lst[base + rank] = tid;
    }
    if (tid == 0) {
        int tot = pfxw[0] + pfxw[1] + pfxw[2] + pfxw[3];
        lst[tot] = row;                   // GATConv self loop
        dgS = tot + 1;
    }
    __syncthreads();
    int dg = dgS;
    for (int p = tid; p < dg * 4; p += 512) {
        int e = p >> 2, hq2 = p & 3;
        int s = lst[e];
        float v = es1[s * 4 + hq2] + ed1[row * 4 + hq2];
        sc[p] = v >= 0.f ? v : 0.2f * v;  // leaky_relu(0.2)
    }
    __syncthreads();
    int hq = tid & 3;
    {
        float lm = -1e30f;
        for (int e = tid >> 2; e < dg; e += 128)
            lm = fmaxf(lm, sc[e * 4 + hq]);
#pragma unroll
        for (int o = 4; o <= 32; o <<= 1) lm = fmaxf(lm, __shfl_xor(lm, o));
        if (lane < 4) sval[wv6 * 4 + hq] = lm;
        __syncthreads();
        float m = sval[hq];
#pragma unroll
        for (int w = 1; w < 8; w++) m = fmaxf(m, sval[w * 4 + hq]);
        float ls = 0.f;
        for (int e = tid >> 2; e < dg; e += 128) {
            float pv = expf(sc[e * 4 + hq] - m);
            sc[e * 4 + hq] = pv;
            ls += pv;
        }
#pragma unroll
        for (int o = 4; o <= 32; o <<= 1) ls += __shfl_xor(ls, o);
        if (lane < 4) sval[32 + wv6 * 4 + hq] = ls;
        __syncthreads();
        float den = sval[32 + hq];
#pragma unroll
        for (int w = 1; w < 8; w++) den += sval[32 + w * 4 + hq];
        for (int e = tid >> 2; e < dg; e += 128)
            sc[e * 4 + hq] = sc[e * 4 + hq] / den;   // alpha
    }
    __syncthreads();
    {
        int col = tid & 255, hh = (tid >> 8) * 2;   // heads {hh, hh+1}
        float acc0 = 0.f, acc1 = 0.f;
        int e = 0;
        for (; e + 8 <= dg; e += 8) {
            float v0[8], v1[8];
#pragma unroll
            for (int u = 0; u < 8; u++) {
                const float* hs = hpre + (size_t)lst[e + u] * M1;
                v0[u] = hs[hh * GCNH + col];
                v1[u] = hs[(hh + 1) * GCNH + col];
            }
#pragma unroll
            for (int u = 0; u < 8; u++) {
                acc0 = fmaf(sc[(e + u) * 4 + hh],     v0[u], acc0);
                acc1 = fmaf(sc[(e + u) * 4 + hh + 1], v1[u], acc1);
            }
        }
        for (; e < dg; e++) {
            const float* hs = hpre + (size_t)lst[e] * M1;
            acc0 = fmaf(sc[e * 4 + hh],     hs[hh * GCNH + col],       acc0);
            acc1 = fmaf(sc[e * 4 + hh + 1], hs[(hh + 1) * GCNH + col], acc1);
        }
        int c0 = hh * GCNH + col, c1 = (hh + 1) * GCNH + col;
        sh[c0] = fmaxf(acc0 + b1[c0], 0.f);
        sh[c1] = fmaxf(acc1 + b1[c1], 0.f);
    }
    __syncthreads();
    if (tid < 504) {                      // 24-way split of 1024 -> 21
        int o = tid % OUTC, pq = tid / OUTC;
        float a2 = 0.f;
        for (int d = pq; d < M1; d += 24)
            a2 = fmaf(sh[d], W2[d * OUTC + o], a2);
        part[pq * OUTC + o] = a2;
    }
    __syncthreads();
    if (tid < OUTC) {
        float ssum = 0.f;
        for (int pq = 0; pq < 24; pq++) ssum += part[pq * OUTC + tid];
        st_wtf(h2 + row * OUTC + tid, ssum);
        h2row[tid] = ssum;
    }
    __syncthreads();
    if (tid == 0) {
        float ssum = 0.f, dd = 0.f;
        for (int k = 0; k < OUTC; k++) {
            ssum = fmaf(h2row[k], as2[k], ssum);
            dd = fmaf(h2row[k], ad2[k], dd);
        }
        st_wtf(es2 + row, ssum);
        st_wtf(ed2 + row, dd);
    }

    gsync(bar, 3 * NN);      // h2/es2/ed2 visible grid-wide

    // ===== stage D: GAT-2 aggregate -> logits + labels ====================
    int dgT = dgS;                        // lst/dgS persist in LDS
    float edt = ed2[row];
    for (int p = tid; p < dgT; p += 512) {
        int s = lst[p];
        float v = es2[s] + edt;
        scD[p] = v >= 0.f ? v : 0.2f * v;
    }
    __syncthreads();
    {
        float lm = -1e30f;
        for (int p = tid; p < dgT; p += 512) lm = fmaxf(lm, scD[p]);
#pragma unroll
        for (int o = 1; o <= 32; o <<= 1) lm = fmaxf(lm, __shfl_xor(lm, o));
        if (lane == 0) sval[wv6] = lm;
        __syncthreads();
        float m = sval[0];
#pragma unroll
        for (int w = 1; w < 8; w++) m = fmaxf(m, sval[w]);
        float ls = 0.f;
        for (int p = tid; p < dgT; p += 512) {
            float pv = expf(scD[p] - m);
            scD[p] = pv;
            ls += pv;
        }
#pragma unroll
        for (int o = 1; o <= 32; o <<= 1) ls += __shfl_xor(ls, o);
        if (lane == 0) sval[8 + wv6] = ls;
        __syncthreads();
        float den = sval[8];
#pragma unroll
        for (int w = 1; w < 8; w++) den += sval[8 + w];
        __syncthreads();
        if (tid < 504) {                  // (edge-group, out-channel) map
            int o = tid % OUTC, eg = tid / OUTC;
            float acc = 0.f;
            for (int e = eg; e < dgT; e += 24) {
                int s = lst[e];
                acc = fmaf(scD[e], h2[(size_t)s * OUTC + o], acc);
            }
            part[eg * OUTC + o] = acc;
        }
        __syncthreads();
        if (tid < OUTC) {
            float ssum = 0.f;
            for (int eg = 0; eg < 24; eg++) ssum += part[eg * OUTC + tid];
            float v = ssum / den + b2[tid];
            out[row * OUTC + tid] = v;
            lv[tid] = v;
        }
    }
    __syncthreads();
    if (tid == 0) {
        int best = 0;
        float bv = lv[0];
        for (int o = 1; o < OUTC; o++)
            if (lv[o] > bv) { bv = lv[o]; best = o; }  // first max wins
        out[NN * OUTC + row] = (float)best;
    }
}

// ---------------------------------------------------------------------------
extern "C" void kernel_launch(void* const* d_in, const int* in_sizes, int n_in,
                              void* d_out, int out_size, void* d_ws,
                              size_t ws_size, hipStream_t stream) {
    const float* feat  = (const float*)d_in[0];
    const float* boxes = (const float*)d_in[1];
    const float* Wfc1  = (const float*)d_in[2];
    const float* bfc1  = (const float*)d_in[3];
    const float* Wfc2  = (const float*)d_in[4];
    const float* bfc2  = (const float*)d_in[5];   (void)bfc2;
    const float* W1    = (const float*)d_in[6];
    const float* as1   = (const float*)d_in[7];
    const float* ad1   = (const float*)d_in[8];
    const float* b1    = (const float*)d_in[9];
    const float* W2    = (const float*)d_in[10];
    const float* as2   = (const float*)d_in[11];
    const float* ad2   = (const float*)d_in[12];
    const float* b2    = (const float*)d_in[13];
    const int*   imh   = (const int*)d_in[14];
    const int*   imw   = (const int*)d_in[15];

    float* ws = (float*)d_ws;
    float* P     = ws;  ws += KC * NN * FCOLS;   // 6,291,456 floats (25 MB)
    float* BT4   = ws;  ws += NN * HIDR;
    float* hpre  = ws;  ws += NN * M1;
    float* es1   = ws;  ws += NN * 4;
    float* ed1   = ws;  ws += NN * 4;
    float* h2    = ws;  ws += NN * OUTC;
    float* es2   = ws;  ws += NN;
    float* ed2   = ws;  ws += NN;
    int* idxTop  = (int*)ws;
    unsigned* bar = (unsigned*)(idxTop + NN * 3);

    float* out = (float*)d_out;

    k_big<<<768, 256, 0, stream>>>(feat, Wfc1, W1, P, bar);
    k_fused<<<NN, 512, 0, stream>>>(P, bfc1, boxes, imh, imw, W1, as1, ad1,
                                    Wfc1, Wfc2, b1, W2, as2, ad2, b2,
                                    BT4, hpre, es1, ed1, idxTop,
                                    h2, es2, ed2, bar, out);
}

// Round 8
// 141.693 us; speedup vs baseline: 1.1882x; 1.0607x over previous
//
#include <hip/hip_runtime.h>
#include <math.h>

#define NN 256
#define FEAT 1024
#define HIDR 256
#define GCNH 256
#define M1 1024            // HEADS*GCNH
#define OUTC 21
#define MAXDEG (NN + 1)    // up to 256 topk-incoming + 1 self loop
#define KC 16              // split-K factor
#define KCH (FEAT / KC)    // 64
#define RB 16              // rows per k_big block
#define FCOLS 1536         // fused output cols: A(256) | B(256) | hpre(1024)

// ---------------------------------------------------------------------------
// DIAGNOSTIC ROUND: the 4-stage persistent kernel is split into 4 dispatches
// so rocprof reports per-stage durations (k_fused has sat at a ~48 µs floor
// for 4 rounds while bottom-up stage models say <=20 µs; this round localizes
// the gap: k_big hidden cost vs a dominant stage vs gsync barrier overhead).
// Kernel boundaries provide ordering -> all stores are plain cached stores.

// ---------------------------------------------------------------------------
// K1: split-K GEMM (round-7 version: LDS-staged feat, register double-
// buffered weights, XCD-aware swizzle, P layout [row][kc][col]).
__global__ __launch_bounds__(256) void k_big(
        const float* __restrict__ feat, const float* __restrict__ Wfc1,
        const float* __restrict__ W1, float* __restrict__ P) {
    int id = blockIdx.x;
    int xcd = id & 7, slot = id >> 3;
    int g = xcd + 8 * (slot >> 4);       // weight group 0..47
    int rg = slot & 15;
    int cgy = g >> 4, kc = g & 15;       // g = cgy*16 + kc
    __shared__ float fS[RB][KCH];
    int tid = threadIdx.x;
    int r0 = rg * RB, k0 = kc * KCH;
    for (int x = tid; x < RB * KCH; x += 256) {
        int r = x >> 6, kk = x & (KCH - 1);
        fS[r][kk] = feat[(size_t)(r0 + r) * FEAT + k0 + kk];
    }
    __syncthreads();
    int gc = cgy * 512 + tid * 2;
    const float* pW;
    int ld;
    if (gc < 256)      { pW = Wfc1 + (size_t)k0 * HIDR + gc;                  ld = HIDR; }
    else if (gc < 512) { pW = Wfc1 + (size_t)(FEAT + k0) * HIDR + (gc - 256); ld = HIDR; }
    else               { pW = W1   + (size_t)k0 * M1 + (gc - 512);            ld = M1;   }
    float2 acc[RB];
#pragma unroll
    for (int r = 0; r < RB; r++) { acc[r].x = 0.f; acc[r].y = 0.f; }
    float2 w0 = *(const float2*)(pW);
    float2 w1 = *(const float2*)(pW + ld);
    float2 w2 = *(const float2*)(pW + 2 * ld);
    float2 w3 = *(const float2*)(pW + 3 * ld);
    for (int kk = 0; kk < KCH; kk += 4) {
        pW += 4 * ld;
        // one-group overshoot bounds: Wfc1 rows <=1027/<=2051, W1 <=1027 — ok
        float2 n0 = *(const float2*)(pW);
        float2 n1 = *(const float2*)(pW + ld);
        float2 n2 = *(const float2*)(pW + 2 * ld);
        float2 n3 = *(const float2*)(pW + 3 * ld);
#pragma unroll
        for (int r = 0; r < RB; r++) {
            float4 f = *(const float4*)&fS[r][kk];
            acc[r].x = fmaf(f.x, w0.x, acc[r].x); acc[r].y = fmaf(f.x, w0.y, acc[r].y);
            acc[r].x = fmaf(f.y, w1.x, acc[r].x); acc[r].y = fmaf(f.y, w1.y, acc[r].y);
            acc[r].x = fmaf(f.z, w2.x, acc[r].x); acc[r].y = fmaf(f.z, w2.y, acc[r].y);
            acc[r].x = fmaf(f.w, w3.x, acc[r].x); acc[r].y = fmaf(f.w, w3.y, acc[r].y);
        }
        w0 = n0; w1 = n1; w2 = n2; w3 = n3;
    }
    float* Pp = P + ((size_t)r0 * KC + kc) * FCOLS + gc;
#pragma unroll
    for (int r = 0; r < RB; r++)
        *(float2*)(Pp + (size_t)r * KC * FCOLS) = acc[r];
}

// ---------------------------------------------------------------------------
// Stage A: split-K reduce + route + geom fixup + es1/ed1 dots. grid 256 x 384.
__global__ __launch_bounds__(384) void k_stA(
        const float* __restrict__ P, const float* __restrict__ bfc1,
        const float* __restrict__ boxes, const int* __restrict__ imh,
        const int* __restrict__ imw, const float* __restrict__ W1,
        const float* __restrict__ as1, const float* __restrict__ ad1,
        float* __restrict__ A, float* __restrict__ BT4,
        float* __restrict__ hpre, float* __restrict__ es1,
        float* __restrict__ ed1) {
    __shared__ float gS[4];
    int row = blockIdx.x, tid = threadIdx.x;
    int c4 = tid * 4;
    const float* p = P + (size_t)row * (KC * FCOLS) + c4;
    float4 a0 = *(const float4*)(p);
    float4 a1 = *(const float4*)(p + FCOLS);
    float4 a2 = *(const float4*)(p + 2 * FCOLS);
    float4 a3 = *(const float4*)(p + 3 * FCOLS);
#pragma unroll
    for (int q = 4; q < KC; q += 4) {
        float4 t0 = *(const float4*)(p + (size_t)q * FCOLS);
        float4 t1 = *(const float4*)(p + (size_t)(q + 1) * FCOLS);
        float4 t2 = *(const float4*)(p + (size_t)(q + 2) * FCOLS);
        float4 t3 = *(const float4*)(p + (size_t)(q + 3) * FCOLS);
        a0.x += t0.x; a0.y += t0.y; a0.z += t0.z; a0.w += t0.w;
        a1.x += t1.x; a1.y += t1.y; a1.z += t1.z; a1.w += t1.w;
        a2.x += t2.x; a2.y += t2.y; a2.z += t2.z; a2.w += t2.w;
        a3.x += t3.x; a3.y += t3.y; a3.z += t3.z; a3.w += t3.w;
    }
    float4 s4;
    s4.x = (a0.x + a1.x) + (a2.x + a3.x);
    s4.y = (a0.y + a1.y) + (a2.y + a3.y);
    s4.z = (a0.z + a1.z) + (a2.z + a3.z);
    s4.w = (a0.w + a1.w) + (a2.w + a3.w);
    if (tid == 0) {
        float w = (float)imw[0], h = (float)imh[0];
        float x1 = boxes[row * 4 + 0] / w, y1 = boxes[row * 4 + 1] / h;
        float x2 = boxes[row * 4 + 2] / w, y2 = boxes[row * 4 + 3] / h;
        gS[0] = x1; gS[1] = y1; gS[2] = x2 - x1; gS[3] = y2 - y1;
    }
    __syncthreads();
    if (c4 < 256) {
        float4 bv = *(const float4*)(bfc1 + c4);
        s4.x += bv.x; s4.y += bv.y; s4.z += bv.z; s4.w += bv.w;
        *(float4*)(A + (size_t)row * HIDR + c4) = s4;
    } else if (c4 < 512) {
        int kk = c4 - 256;
        *(float4*)(BT4 + (size_t)(kk >> 2) * (NN * 4) + row * 4) = s4;
    } else {
        int ch = c4 - 512;
        float g0 = gS[0], g1 = gS[1], g2 = gS[2], g3 = gS[3];
        float4 wv;
        wv = *(const float4*)(W1 + (size_t)(FEAT + 0) * M1 + ch);
        s4.x = fmaf(g0, wv.x, s4.x); s4.y = fmaf(g0, wv.y, s4.y);
        s4.z = fmaf(g0, wv.z, s4.z); s4.w = fmaf(g0, wv.w, s4.w);
        wv = *(const float4*)(W1 + (size_t)(FEAT + 1) * M1 + ch);
        s4.x = fmaf(g1, wv.x, s4.x); s4.y = fmaf(g1, wv.y, s4.y);
        s4.z = fmaf(g1, wv.z, s4.z); s4.w = fmaf(g1, wv.w, s4.w);
        wv = *(const float4*)(W1 + (size_t)(FEAT + 2) * M1 + ch);
        s4.x = fmaf(g2, wv.x, s4.x); s4.y = fmaf(g2, wv.y, s4.y);
        s4.z = fmaf(g2, wv.z, s4.z); s4.w = fmaf(g2, wv.w, s4.w);
        wv = *(const float4*)(W1 + (size_t)(FEAT + 3) * M1 + ch);
        s4.x = fmaf(g3, wv.x, s4.x); s4.y = fmaf(g3, wv.y, s4.y);
        s4.z = fmaf(g3, wv.z, s4.z); s4.w = fmaf(g3, wv.w, s4.w);
        *(float4*)(hpre + (size_t)row * M1 + ch) = s4;
        float4 a = *(const float4*)(as1 + ch);
        float4 bv = *(const float4*)(ad1 + ch);
        float ps = s4.x * a.x + s4.y * a.y + s4.z * a.z + s4.w * a.w;
        float pd = s4.x * bv.x + s4.y * bv.y + s4.z * bv.z + s4.w * bv.w;
#pragma unroll
        for (int o = 32; o > 0; o >>= 1) {
            ps += __shfl_down(ps, o);
            pd += __shfl_down(pd, o);
        }
        if ((tid & 63) == 0) {
            int head = (tid - 128) >> 6;
            es1[row * 4 + head] = ps;
            ed1[row * 4 + head] = pd;
        }
    }
}

// ---------------------------------------------------------------------------
// Stage B: fused rel-row + top-3. grid 256 x 512.
__global__ __launch_bounds__(512) void k_stB(
        const float* __restrict__ A, const float* __restrict__ boxes,
        const float* __restrict__ Wfc1, const float* __restrict__ Wfc2,
        const float* __restrict__ BT4, int* __restrict__ idxTop) {
    __shared__ float As[HIDR];
    __shared__ float sval[512];
    __shared__ unsigned long long swk[8];
    __shared__ int win;
    int row = blockIdx.x, tid = threadIdx.x;
    if (tid < 256) As[tid] = A[(size_t)row * HIDR + tid];
    int j = tid & 255;
    float bi0 = boxes[row * 4 + 0], bi1 = boxes[row * 4 + 1];
    float bi2 = boxes[row * 4 + 2], bi3 = boxes[row * 4 + 3];
    float g0 = fabsf(bi0 - boxes[j * 4 + 0]);
    float g1 = fabsf(bi1 - boxes[j * 4 + 1]);
    float g2 = fabsf(bi2 - boxes[j * 4 + 2]);
    float g3 = fabsf(bi3 - boxes[j * 4 + 3]);
    __syncthreads();
    {
        int half = __builtin_amdgcn_readfirstlane(tid >> 8);  // wave-uniform
        int k0 = half * 128;
        const float* pB  = BT4 + (size_t)(k0 >> 2) * (NN * 4) + j * 4;
        const float* pA  = As + k0;                 // LDS broadcast
        const float* pW2 = Wfc2 + k0;
        const float* pg0 = Wfc1 + (size_t)(2 * FEAT + 0) * HIDR + k0;
        const float* pg1 = Wfc1 + (size_t)(2 * FEAT + 1) * HIDR + k0;
        const float* pg2 = Wfc1 + (size_t)(2 * FEAT + 2) * HIDR + k0;
        const float* pg3 = Wfc1 + (size_t)(2 * FEAT + 3) * HIDR + k0;
        float acc = 0.f;
#pragma unroll 4
        for (int kk = 0; kk < 128; kk += 4) {
            float4 a4 = *(const float4*)(pA + kk);
            float4 w4 = *(const float4*)(pW2 + kk);
            float4 q0 = *(const float4*)(pg0 + kk);
            float4 q1 = *(const float4*)(pg1 + kk);
            float4 q2 = *(const float4*)(pg2 + kk);
            float4 q3 = *(const float4*)(pg3 + kk);
            float4 b4 = *(const float4*)pB;
            pB += NN * 4;
            float v;
            v = a4.x + b4.x; v = fmaf(g0, q0.x, v); v = fmaf(g1, q1.x, v);
            v = fmaf(g2, q2.x, v); v = fmaf(g3, q3.x, v);
            acc = fmaf(fmaxf(v, 0.f), w4.x, acc);
            v = a4.y + b4.y; v = fmaf(g0, q0.y, v); v = fmaf(g1, q1.y, v);
            v = fmaf(g2, q2.y, v); v = fmaf(g3, q3.y, v);
            acc = fmaf(fmaxf(v, 0.f), w4.y, acc);
            v = a4.z + b4.z; v = fmaf(g0, q0.z, v); v = fmaf(g1, q1.z, v);
            v = fmaf(g2, q2.z, v); v = fmaf(g3, q3.z, v);
            acc = fmaf(fmaxf(v, 0.f), w4.z, acc);
            v = a4.w + b4.w; v = fmaf(g0, q0.w, v); v = fmaf(g1, q1.w, v);
            v = fmaf(g2, q2.w, v); v = fmaf(g3, q3.w, v);
            acc = fmaf(fmaxf(v, 0.f), w4.w, acc);
        }
        sval[tid] = acc;
    }
    __syncthreads();
    if (tid < 256) sval[tid] = sval[tid] + sval[tid + 256];
    __syncthreads();
    for (int r = 0; r < 4; r++) {
        unsigned long long key = 0ULL;
        if (tid < 256) {
            unsigned u = __float_as_uint(sval[tid]);
            u = (u & 0x80000000u) ? ~u : (u | 0x80000000u);
            key = ((unsigned long long)u << 32) | (unsigned)(NN - 1 - tid);
        }
#pragma unroll
        for (int o = 32; o > 0; o >>= 1) {
            unsigned long long nk = __shfl_down(key, o);
            if (nk > key) key = nk;
        }
        if ((tid & 63) == 0) swk[tid >> 6] = key;
        __syncthreads();
        if (tid == 0) {
            unsigned long long m = swk[0];
#pragma unroll
            for (int q = 1; q < 8; q++) if (swk[q] > m) m = swk[q];
            int wj = NN - 1 - (int)(m & 0xFFFFFFFFu);
            win = wj;
            if (r > 0) idxTop[row * 3 + (r - 1)] = wj;
        }
        __syncthreads();
        if (tid == win) sval[tid] = -1e38f;
        __syncthreads();
    }
}

// ---------------------------------------------------------------------------
// Stage C: ballot edge build + GAT-1 softmax/aggregate + h2 + es2/ed2.
// grid 256 x 512. Persists lst/deg to global for stage D.
__global__ __launch_bounds__(512) void k_stC(
        const int* __restrict__ idxTop, const float* __restrict__ es1,
        const float* __restrict__ ed1, const float* __restrict__ hpre,
        const float* __restrict__ b1, const float* __restrict__ W2,
        const float* __restrict__ as2, const float* __restrict__ ad2,
        int* __restrict__ deg, int* __restrict__ inlist,
        float* __restrict__ h2, float* __restrict__ es2,
        float* __restrict__ ed2) {
    __shared__ float sval[512];
    __shared__ int pfxw[4];
    __shared__ int lst[MAXDEG];
    __shared__ int dgS;
    __shared__ float sc[MAXDEG * 4];
    __shared__ float sh[M1];
    __shared__ float part[24 * OUTC];
    __shared__ float h2row[OUTC];
    int row = blockIdx.x, tid = threadIdx.x;
    int f = 0;
    if (tid < 256)
        f = (idxTop[tid * 3 + 0] == row) | (idxTop[tid * 3 + 1] == row)
          | (idxTop[tid * 3 + 2] == row);
    unsigned long long bm = __ballot(f);
    int lane = tid & 63, wv6 = tid >> 6;
    int rank = __popcll(bm & ((1ULL << lane) - 1ULL));
    if (tid < 256 && lane == 0) pfxw[wv6] = __popcll(bm);
    __syncthreads();
    {
        int base = 0;
#pragma unroll
        for (int w = 0; w < 4; w++) base += (w < wv6) ? pfxw[w] : 0;
        if (tid < 256 && f) {
            lst[base + rank] = tid;
            inlist[row * MAXDEG + base + rank] = tid;
        }
    }
    if (tid == 0) {
        int tot = pfxw[0] + pfxw[1] + pfxw[2] + pfxw[3];
        lst[tot] = row;                   // GATConv self loop
        inlist[row * MAXDEG + tot] = row;
        dgS = tot + 1;
        deg[row] = tot + 1;
    }
    __syncthreads();
    int dg = dgS;
    for (int p = tid; p < dg * 4; p += 512) {
        int e = p >> 2, hq2 = p & 3;
        int s = lst[e];
        float v = es1[s * 4 + hq2] + ed1[row * 4 + hq2];
        sc[p] = v >= 0.f ? v : 0.2f * v;  // leaky_relu(0.2)
    }
    __syncthreads();
    int hq = tid & 3;
    {
        float lm = -1e30f;
        for (int e = tid >> 2; e < dg; e += 128)
            lm = fmaxf(lm, sc[e * 4 + hq]);
#pragma unroll
        for (int o = 4; o <= 32; o <<= 1) lm = fmaxf(lm, __shfl_xor(lm, o));
        if (lane < 4) sval[wv6 * 4 + hq] = lm;
        __syncthreads();
        float m = sval[hq];
#pragma unroll
        for (int w = 1; w < 8; w++) m = fmaxf(m, sval[w * 4 + hq]);
        float ls = 0.f;
        for (int e = tid >> 2; e < dg; e += 128) {
            float pv = expf(sc[e * 4 + hq] - m);
            sc[e * 4 + hq] = pv;
            ls += pv;
        }
#pragma unroll
        for (int o = 4; o <= 32; o <<= 1) ls += __shfl_xor(ls, o);
        if (lane < 4) sval[32 + wv6 * 4 + hq] = ls;
        __syncthreads();
        float den = sval[32 + hq];
#pragma unroll
        for (int w = 1; w < 8; w++) den += sval[32 + w * 4 + hq];
        for (int e = tid >> 2; e < dg; e += 128)
            sc[e * 4 + hq] = sc[e * 4 + hq] / den;   // alpha
    }
    __syncthreads();
    {
        int col = tid & 255, hh = (tid >> 8) * 2;   // heads {hh, hh+1}
        float acc0 = 0.f, acc1 = 0.f;
        int e = 0;
        for (; e + 8 <= dg; e += 8) {
            float v0[8], v1[8];
#pragma unroll
            for (int u = 0; u < 8; u++) {
                const float* hs = hpre + (size_t)lst[e + u] * M1;
                v0[u] = hs[hh * GCNH + col];
                v1[u] = hs[(hh + 1) * GCNH + col];
            }
#pragma unroll
            for (int u = 0; u < 8; u++) {
                acc0 = fmaf(sc[(e + u) * 4 + hh],     v0[u], acc0);
                acc1 = fmaf(sc[(e + u) * 4 + hh + 1], v1[u], acc1);
            }
        }
        for (; e < dg; e++) {
            const float* hs = hpre + (size_t)lst[e] * M1;
            acc0 = fmaf(sc[e * 4 + hh],     hs[hh * GCNH + col],       acc0);
            acc1 = fmaf(sc[e * 4 + hh + 1], hs[(hh + 1) * GCNH + col], acc1);
        }
        int c0 = hh * GCNH + col, c1 = (hh + 1) * GCNH + col;
        sh[c0] = fmaxf(acc0 + b1[c0], 0.f);
        sh[c1] = fmaxf(acc1 + b1[c1], 0.f);
    }
    __syncthreads();
    if (tid < 504) {                      // 24-way split of 1024 -> 21
        int o = tid % OUTC, pq = tid / OUTC;
        float a2 = 0.f;
        for (int d = pq; d < M1; d += 24)
            a2 = fmaf(sh[d], W2[d * OUTC + o], a2);
        part[pq * OUTC + o] = a2;
    }
    __syncthreads();
    if (tid < OUTC) {
        float ssum = 0.f;
        for (int pq = 0; pq < 24; pq++) ssum += part[pq * OUTC + tid];
        h2[row * OUTC + tid] = ssum;
        h2row[tid] = ssum;
    }
    __syncthreads();
    if (tid == 0) {
        float ssum = 0.f, dd = 0.f;
        for (int k = 0; k < OUTC; k++) {
            ssum = fmaf(h2row[k], as2[k], ssum);
            dd = fmaf(h2row[k], ad2[k], dd);
        }
        es2[row] = ssum;
        ed2[row] = dd;
    }
}

// ---------------------------------------------------------------------------
// Stage D: GAT-2 softmax-aggregate -> logits + argmax. grid 256 x 512.
__global__ __launch_bounds__(512) void k_stD(
        const int* __restrict__ deg, const int* __restrict__ inlist,
        const float* __restrict__ es2, const float* __restrict__ ed2,
        const float* __restrict__ h2, const float* __restrict__ b2,
        float* __restrict__ out) {
    __shared__ float sval[512];
    __shared__ int lst[MAXDEG];
    __shared__ float scD[MAXDEG];
    __shared__ float part[24 * OUTC];
    __shared__ float lv[OUTC];
    int row = blockIdx.x, tid = threadIdx.x;
    int lane = tid & 63, wv6 = tid >> 6;
    int dgT = deg[row];
    float edt = ed2[row];
    for (int p = tid; p < dgT; p += 512) {
        int s = inlist[row * MAXDEG + p];
        lst[p] = s;
        float v = es2[s] + edt;
        scD[p] = v >= 0.f ? v : 0.2f * v;
    }
    __syncthreads();
    {
        float lm = -1e30f;
        for (int p = tid; p < dgT; p += 512) lm = fmaxf(lm, scD[p]);
#pragma unroll
        for (int o = 1; o <= 32; o <<= 1) lm = fmaxf(lm, __shfl_xor(lm, o));
        if (lane == 0) sval[wv6] = lm;
        __syncthreads();
        float m = sval[0];
#pragma unroll
        for (int w = 1; w < 8; w++) m = fmaxf(m, sval[w]);
        float ls = 0.f;
        for (int p = tid; p < dgT; p += 512) {
            float pv = expf(scD[p] - m);
            scD[p] = pv;
            ls += pv;
        }
#pragma unroll
        for (int o = 1; o <= 32; o <<= 1) ls += __shfl_xor(ls, o);
        if (lane == 0) sval[8 + wv6] = ls;
        __syncthreads();
        float den = sval[8];
#pragma unroll
        for (int w = 1; w < 8; w++) den += sval[8 + w];
        __syncthreads();
        if (tid < 504) {                  // (edge-group, out-channel) map
            int o = tid % OUTC, eg = tid / OUTC;
            float acc = 0.f;
            for (int e = eg; e < dgT; e += 24) {
                int s = lst[e];
                acc = fmaf(scD[e], h2[(size_t)s * OUTC + o], acc);
            }
            part[eg * OUTC + o] = acc;
        }
        __syncthreads();
        if (tid < OUTC) {
            float ssum = 0.f;
            for (int eg = 0; eg < 24; eg++) ssum += part[eg * OUTC + tid];
            float v = ssum / den + b2[tid];
            out[row * OUTC + tid] = v;
            lv[tid] = v;
        }
    }
    __syncthreads();
    if (tid == 0) {
        int best = 0;
        float bv = lv[0];
        for (int o = 1; o < OUTC; o++)
            if (lv[o] > bv) { bv = lv[o]; best = o; }  // first max wins
        out[NN * OUTC + row] = (float)best;
    }
}

// ---------------------------------------------------------------------------
extern "C" void kernel_launch(void* const* d_in, const int* in_sizes, int n_in,
                              void* d_out, int out_size, void* d_ws,
                              size_t ws_size, hipStream_t stream) {
    const float* feat  = (const float*)d_in[0];
    const float* boxes = (const float*)d_in[1];
    const float* Wfc1  = (const float*)d_in[2];
    const float* bfc1  = (const float*)d_in[3];
    const float* Wfc2  = (const float*)d_in[4];
    const float* bfc2  = (const float*)d_in[5];   (void)bfc2;
    const float* W1    = (const float*)d_in[6];
    const float* as1   = (const float*)d_in[7];
    const float* ad1   = (const float*)d_in[8];
    const float* b1    = (const float*)d_in[9];
    const float* W2    = (const float*)d_in[10];
    const float* as2   = (const float*)d_in[11];
    const float* ad2   = (const float*)d_in[12];
    const float* b2    = (const float*)d_in[13];
    const int*   imh   = (const int*)d_in[14];
    const int*   imw   = (const int*)d_in[15];

    float* ws = (float*)d_ws;
    float* P     = ws;  ws += KC * NN * FCOLS;   // 25 MB
    float* A     = ws;  ws += NN * HIDR;
    float* BT4   = ws;  ws += NN * HIDR;
    float* hpre  = ws;  ws += NN * M1;
    float* es1   = ws;  ws += NN * 4;
    float* ed1   = ws;  ws += NN * 4;
    float* h2    = ws;  ws += NN * OUTC;
    float* es2   = ws;  ws += NN;
    float* ed2   = ws;  ws += NN;
    int* idxTop  = (int*)ws;
    int* deg     = idxTop + NN * 3;
    int* inlist  = deg + NN;

    float* out = (float*)d_out;

    k_big<<<768, 256, 0, stream>>>(feat, Wfc1, W1, P);
    k_stA<<<NN, 384, 0, stream>>>(P, bfc1, boxes, imh, imw, W1, as1, ad1,
                                  A, BT4, hpre, es1, ed1);
    k_stB<<<NN, 512, 0, stream>>>(A, boxes, Wfc1, Wfc2, BT4, idxTop);
    k_stC<<<NN, 512, 0, stream>>>(idxTop, es1, ed1, hpre, b1, W2, as2, ad2,
                                  deg, inlist, h2, es2, ed2);
    k_stD<<<NN, 512, 0, stream>>>(deg, inlist, es2, ed2, h2, b2, out);
}

// Round 9
// 139.873 us; speedup vs baseline: 1.2037x; 1.0130x over previous
//
#include <hip/hip_runtime.h>
#include <math.h>

#define NN 256
#define FEAT 1024
#define HIDR 256
#define GCNH 256
#define M1 1024            // HEADS*GCNH
#define OUTC 21
#define MAXDEG (NN + 1)    // up to 256 topk-incoming + 1 self loop
#define KC 16              // split-K factor
#define KCH (FEAT / KC)    // 64
#define RB 16              // rows per k_big block
#define FCOLS 1536         // fused output cols: A(256) | B(256) | hpre(1024)

// ---------------------------------------------------------------------------
// 5-dispatch pipeline (round-8 structure, measured best 141.7 µs; kernel
// boundaries beat in-kernel grid barriers). This round: k_big prefetch
// depth 2 — k_big is latency-bound (~45 µs inferred, unique bytes ~7 MB,
// fma ~5 µs): 3 waves/SIMD x 256 cyc/round couldn't hide ~900 cyc cold-HBM
// weight misses. 8 rows in flight -> 512 cyc/round x 3 waves = 1536 cyc.

// ---------------------------------------------------------------------------
// K1: split-K GEMM. LDS-staged feat, XCD-aware swizzle, P [row][kc][col],
// register prefetch DEPTH 2 (w0..3 = k..k+3, x0..3 = k+4..k+7; next 8 issued
// before compute). Epilogue handles the last 8 rows -> no overshoot reads.
__global__ __launch_bounds__(256) void k_big(
        const float* __restrict__ feat, const float* __restrict__ Wfc1,
        const float* __restrict__ W1, float* __restrict__ P) {
    int id = blockIdx.x;
    int xcd = id & 7, slot = id >> 3;
    int g = xcd + 8 * (slot >> 4);       // weight group 0..47
    int rg = slot & 15;
    int cgy = g >> 4, kc = g & 15;       // g = cgy*16 + kc
    __shared__ float fS[RB][KCH];
    int tid = threadIdx.x;
    int r0 = rg * RB, k0 = kc * KCH;
    for (int x = tid; x < RB * KCH; x += 256) {
        int r = x >> 6, kk = x & (KCH - 1);
        fS[r][kk] = feat[(size_t)(r0 + r) * FEAT + k0 + kk];
    }
    __syncthreads();
    int gc = cgy * 512 + tid * 2;
    const float* pW;
    int ld;
    if (gc < 256)      { pW = Wfc1 + (size_t)k0 * HIDR + gc;                  ld = HIDR; }
    else if (gc < 512) { pW = Wfc1 + (size_t)(FEAT + k0) * HIDR + (gc - 256); ld = HIDR; }
    else               { pW = W1   + (size_t)k0 * M1 + (gc - 512);            ld = M1;   }
    float2 acc[RB];
#pragma unroll
    for (int r = 0; r < RB; r++) { acc[r].x = 0.f; acc[r].y = 0.f; }
    float2 w0 = *(const float2*)(pW);
    float2 w1 = *(const float2*)(pW + ld);
    float2 w2 = *(const float2*)(pW + 2 * ld);
    float2 w3 = *(const float2*)(pW + 3 * ld);
    float2 x0 = *(const float2*)(pW + 4 * ld);
    float2 x1 = *(const float2*)(pW + 5 * ld);
    float2 x2 = *(const float2*)(pW + 6 * ld);
    float2 x3 = *(const float2*)(pW + 7 * ld);
    for (int kk = 0; kk < KCH - 8; kk += 8) {
        pW += 8 * ld;
        float2 n0 = *(const float2*)(pW);
        float2 n1 = *(const float2*)(pW + ld);
        float2 n2 = *(const float2*)(pW + 2 * ld);
        float2 n3 = *(const float2*)(pW + 3 * ld);
        float2 m0 = *(const float2*)(pW + 4 * ld);
        float2 m1 = *(const float2*)(pW + 5 * ld);
        float2 m2 = *(const float2*)(pW + 6 * ld);
        float2 m3 = *(const float2*)(pW + 7 * ld);
#pragma unroll
        for (int r = 0; r < RB; r++) {
            float4 f = *(const float4*)&fS[r][kk];
            float4 h = *(const float4*)&fS[r][kk + 4];
            acc[r].x = fmaf(f.x, w0.x, acc[r].x); acc[r].y = fmaf(f.x, w0.y, acc[r].y);
            acc[r].x = fmaf(f.y, w1.x, acc[r].x); acc[r].y = fmaf(f.y, w1.y, acc[r].y);
            acc[r].x = fmaf(f.z, w2.x, acc[r].x); acc[r].y = fmaf(f.z, w2.y, acc[r].y);
            acc[r].x = fmaf(f.w, w3.x, acc[r].x); acc[r].y = fmaf(f.w, w3.y, acc[r].y);
            acc[r].x = fmaf(h.x, x0.x, acc[r].x); acc[r].y = fmaf(h.x, x0.y, acc[r].y);
            acc[r].x = fmaf(h.y, x1.x, acc[r].x); acc[r].y = fmaf(h.y, x1.y, acc[r].y);
            acc[r].x = fmaf(h.z, x2.x, acc[r].x); acc[r].y = fmaf(h.z, x2.y, acc[r].y);
            acc[r].x = fmaf(h.w, x3.x, acc[r].x); acc[r].y = fmaf(h.w, x3.y, acc[r].y);
        }
        w0 = n0; w1 = n1; w2 = n2; w3 = n3;
        x0 = m0; x1 = m1; x2 = m2; x3 = m3;
    }
    {   // epilogue: last 8 k-rows (kk = KCH-8), no prefetch, no overshoot
        const int kk = KCH - 8;
#pragma unroll
        for (int r = 0; r < RB; r++) {
            float4 f = *(const float4*)&fS[r][kk];
            float4 h = *(const float4*)&fS[r][kk + 4];
            acc[r].x = fmaf(f.x, w0.x, acc[r].x); acc[r].y = fmaf(f.x, w0.y, acc[r].y);
            acc[r].x = fmaf(f.y, w1.x, acc[r].x); acc[r].y = fmaf(f.y, w1.y, acc[r].y);
            acc[r].x = fmaf(f.z, w2.x, acc[r].x); acc[r].y = fmaf(f.z, w2.y, acc[r].y);
            acc[r].x = fmaf(f.w, w3.x, acc[r].x); acc[r].y = fmaf(f.w, w3.y, acc[r].y);
            acc[r].x = fmaf(h.x, x0.x, acc[r].x); acc[r].y = fmaf(h.x, x0.y, acc[r].y);
            acc[r].x = fmaf(h.y, x1.x, acc[r].x); acc[r].y = fmaf(h.y, x1.y, acc[r].y);
            acc[r].x = fmaf(h.z, x2.x, acc[r].x); acc[r].y = fmaf(h.z, x2.y, acc[r].y);
            acc[r].x = fmaf(h.w, x3.x, acc[r].x); acc[r].y = fmaf(h.w, x3.y, acc[r].y);
        }
    }
    float* Pp = P + ((size_t)r0 * KC + kc) * FCOLS + gc;
#pragma unroll
    for (int r = 0; r < RB; r++)
        *(float2*)(Pp + (size_t)r * KC * FCOLS) = acc[r];
}

// ---------------------------------------------------------------------------
// Stage A: split-K reduce + route + geom fixup + es1/ed1 dots. grid 256 x 384.
__global__ __launch_bounds__(384) void k_stA(
        const float* __restrict__ P, const float* __restrict__ bfc1,
        const float* __restrict__ boxes, const int* __restrict__ imh,
        const int* __restrict__ imw, const float* __restrict__ W1,
        const float* __restrict__ as1, const float* __restrict__ ad1,
        float* __restrict__ A, float* __restrict__ BT4,
        float* __restrict__ hpre, float* __restrict__ es1,
        float* __restrict__ ed1) {
    __shared__ float gS[4];
    int row = blockIdx.x, tid = threadIdx.x;
    int c4 = tid * 4;
    const float* p = P + (size_t)row * (KC * FCOLS) + c4;
    float4 a0 = *(const float4*)(p);
    float4 a1 = *(const float4*)(p + FCOLS);
    float4 a2 = *(const float4*)(p + 2 * FCOLS);
    float4 a3 = *(const float4*)(p + 3 * FCOLS);
#pragma unroll
    for (int q = 4; q < KC; q += 4) {
        float4 t0 = *(const float4*)(p + (size_t)q * FCOLS);
        float4 t1 = *(const float4*)(p + (size_t)(q + 1) * FCOLS);
        float4 t2 = *(const float4*)(p + (size_t)(q + 2) * FCOLS);
        float4 t3 = *(const float4*)(p + (size_t)(q + 3) * FCOLS);
        a0.x += t0.x; a0.y += t0.y; a0.z += t0.z; a0.w += t0.w;
        a1.x += t1.x; a1.y += t1.y; a1.z += t1.z; a1.w += t1.w;
        a2.x += t2.x; a2.y += t2.y; a2.z += t2.z; a2.w += t2.w;
        a3.x += t3.x; a3.y += t3.y; a3.z += t3.z; a3.w += t3.w;
    }
    float4 s4;
    s4.x = (a0.x + a1.x) + (a2.x + a3.x);
    s4.y = (a0.y + a1.y) + (a2.y + a3.y);
    s4.z = (a0.z + a1.z) + (a2.z + a3.z);
    s4.w = (a0.w + a1.w) + (a2.w + a3.w);
    if (tid == 0) {
        float w = (float)imw[0], h = (float)imh[0];
        float x1 = boxes[row * 4 + 0] / w, y1 = boxes[row * 4 + 1] / h;
        float x2 = boxes[row * 4 + 2] / w, y2 = boxes[row * 4 + 3] / h;
        gS[0] = x1; gS[1] = y1; gS[2] = x2 - x1; gS[3] = y2 - y1;
    }
    __syncthreads();
    if (c4 < 256) {
        float4 bv = *(const float4*)(bfc1 + c4);
        s4.x += bv.x; s4.y += bv.y; s4.z += bv.z; s4.w += bv.w;
        *(float4*)(A + (size_t)row * HIDR + c4) = s4;
    } else if (c4 < 512) {
        int kk = c4 - 256;
        *(float4*)(BT4 + (size_t)(kk >> 2) * (NN * 4) + row * 4) = s4;
    } else {
        int ch = c4 - 512;
        float g0 = gS[0], g1 = gS[1], g2 = gS[2], g3 = gS[3];
        float4 wv;
        wv = *(const float4*)(W1 + (size_t)(FEAT + 0) * M1 + ch);
        s4.x = fmaf(g0, wv.x, s4.x); s4.y = fmaf(g0, wv.y, s4.y);
        s4.z = fmaf(g0, wv.z, s4.z); s4.w = fmaf(g0, wv.w, s4.w);
        wv = *(const float4*)(W1 + (size_t)(FEAT + 1) * M1 + ch);
        s4.x = fmaf(g1, wv.x, s4.x); s4.y = fmaf(g1, wv.y, s4.y);
        s4.z = fmaf(g1, wv.z, s4.z); s4.w = fmaf(g1, wv.w, s4.w);
        wv = *(const float4*)(W1 + (size_t)(FEAT + 2) * M1 + ch);
        s4.x = fmaf(g2, wv.x, s4.x); s4.y = fmaf(g2, wv.y, s4.y);
        s4.z = fmaf(g2, wv.z, s4.z); s4.w = fmaf(g2, wv.w, s4.w);
        wv = *(const float4*)(W1 + (size_t)(FEAT + 3) * M1 + ch);
        s4.x = fmaf(g3, wv.x, s4.x); s4.y = fmaf(g3, wv.y, s4.y);
        s4.z = fmaf(g3, wv.z, s4.z); s4.w = fmaf(g3, wv.w, s4.w);
        *(float4*)(hpre + (size_t)row * M1 + ch) = s4;
        float4 a = *(const float4*)(as1 + ch);
        float4 bv = *(const float4*)(ad1 + ch);
        float ps = s4.x * a.x + s4.y * a.y + s4.z * a.z + s4.w * a.w;
        float pd = s4.x * bv.x + s4.y * bv.y + s4.z * bv.z + s4.w * bv.w;
#pragma unroll
        for (int o = 32; o > 0; o >>= 1) {
            ps += __shfl_down(ps, o);
            pd += __shfl_down(pd, o);
        }
        if ((tid & 63) == 0) {
            int head = (tid - 128) >> 6;
            es1[row * 4 + head] = ps;
            ed1[row * 4 + head] = pd;
        }
    }
}

// ---------------------------------------------------------------------------
// Stage B: fused rel-row + top-3. grid 256 x 512.
__global__ __launch_bounds__(512) void k_stB(
        const float* __restrict__ A, const float* __restrict__ boxes,
        const float* __restrict__ Wfc1, const float* __restrict__ Wfc2,
        const float* __restrict__ BT4, int* __restrict__ idxTop) {
    __shared__ float As[HIDR];
    __shared__ float sval[512];
    __shared__ unsigned long long swk[8];
    __shared__ int win;
    int row = blockIdx.x, tid = threadIdx.x;
    if (tid < 256) As[tid] = A[(size_t)row * HIDR + tid];
    int j = tid & 255;
    float bi0 = boxes[row * 4 + 0], bi1 = boxes[row * 4 + 1];
    float bi2 = boxes[row * 4 + 2], bi3 = boxes[row * 4 + 3];
    float g0 = fabsf(bi0 - boxes[j * 4 + 0]);
    float g1 = fabsf(bi1 - boxes[j * 4 + 1]);
    float g2 = fabsf(bi2 - boxes[j * 4 + 2]);
    float g3 = fabsf(bi3 - boxes[j * 4 + 3]);
    __syncthreads();
    {
        int half = __builtin_amdgcn_readfirstlane(tid >> 8);  // wave-uniform
        int k0 = half * 128;
        const float* pB  = BT4 + (size_t)(k0 >> 2) * (NN * 4) + j * 4;
        const float* pA  = As + k0;                 // LDS broadcast
        const float* pW2 = Wfc2 + k0;
        const float* pg0 = Wfc1 + (size_t)(2 * FEAT + 0) * HIDR + k0;
        const float* pg1 = Wfc1 + (size_t)(2 * FEAT + 1) * HIDR + k0;
        const float* pg2 = Wfc1 + (size_t)(2 * FEAT + 2) * HIDR + k0;
        const float* pg3 = Wfc1 + (size_t)(2 * FEAT + 3) * HIDR + k0;
        float acc = 0.f;
#pragma unroll 4
        for (int kk = 0; kk < 128; kk += 4) {
            float4 a4 = *(const float4*)(pA + kk);
            float4 w4 = *(const float4*)(pW2 + kk);
            float4 q0 = *(const float4*)(pg0 + kk);
            float4 q1 = *(const float4*)(pg1 + kk);
            float4 q2 = *(const float4*)(pg2 + kk);
            float4 q3 = *(const float4*)(pg3 + kk);
            float4 b4 = *(const float4*)pB;
            pB += NN * 4;
            float v;
            v = a4.x + b4.x; v = fmaf(g0, q0.x, v); v = fmaf(g1, q1.x, v);
            v = fmaf(g2, q2.x, v); v = fmaf(g3, q3.x, v);
            acc = fmaf(fmaxf(v, 0.f), w4.x, acc);
            v = a4.y + b4.y; v = fmaf(g0, q0.y, v); v = fmaf(g1, q1.y, v);
            v = fmaf(g2, q2.y, v); v = fmaf(g3, q3.y, v);
            acc = fmaf(fmaxf(v, 0.f), w4.y, acc);
            v = a4.z + b4.z; v = fmaf(g0, q0.z, v); v = fmaf(g1, q1.z, v);
            v = fmaf(g2, q2.z, v); v = fmaf(g3, q3.z, v);
            acc = fmaf(fmaxf(v, 0.f), w4.z, acc);
            v = a4.w + b4.w; v = fmaf(g0, q0.w, v); v = fmaf(g1, q1.w, v);
            v = fmaf(g2, q2.w, v); v = fmaf(g3, q3.w, v);
            acc = fmaf(fmaxf(v, 0.f), w4.w, acc);
        }
        sval[tid] = acc;
    }
    __syncthreads();
    if (tid < 256) sval[tid] = sval[tid] + sval[tid + 256];
    __syncthreads();
    for (int r = 0; r < 4; r++) {
        unsigned long long key = 0ULL;
        if (tid < 256) {
            unsigned u = __float_as_uint(sval[tid]);
            u = (u & 0x80000000u) ? ~u : (u | 0x80000000u);
            key = ((unsigned long long)u << 32) | (unsigned)(NN - 1 - tid);
        }
#pragma unroll
        for (int o = 32; o > 0; o >>= 1) {
            unsigned long long nk = __shfl_down(key, o);
            if (nk > key) key = nk;
        }
        if ((tid & 63) == 0) swk[tid >> 6] = key;
        __syncthreads();
        if (tid == 0) {
            unsigned long long m = swk[0];
#pragma unroll
            for (int q = 1; q < 8; q++) if (swk[q] > m) m = swk[q];
            int wj = NN - 1 - (int)(m & 0xFFFFFFFFu);
            win = wj;
            if (r > 0) idxTop[row * 3 + (r - 1)] = wj;
        }
        __syncthreads();
        if (tid == win) sval[tid] = -1e38f;
        __syncthreads();
    }
}

// ---------------------------------------------------------------------------
// Stage C: ballot edge build + GAT-1 softmax/aggregate + h2 + es2/ed2.
// grid 256 x 512. Persists lst/deg to global for stage D.
__global__ __launch_bounds__(512) void k_stC(
        const int* __restrict__ idxTop, const float* __restrict__ es1,
        const float* __restrict__ ed1, const float* __restrict__ hpre,
        const float* __restrict__ b1, const float* __restrict__ W2,
        const float* __restrict__ as2, const float* __restrict__ ad2,
        int* __restrict__ deg, int* __restrict__ inlist,
        float* __restrict__ h2, float* __restrict__ es2,
        float* __restrict__ ed2) {
    __shared__ float sval[512];
    __shared__ int pfxw[4];
    __shared__ int lst[MAXDEG];
    __shared__ int dgS;
    __shared__ float sc[MAXDEG * 4];
    __shared__ float sh[M1];
    __shared__ float part[24 * OUTC];
    __shared__ float h2row[OUTC];
    int row = blockIdx.x, tid = threadIdx.x;
    int f = 0;
    if (tid < 256)
        f = (idxTop[tid * 3 + 0] == row) | (idxTop[tid * 3 + 1] == row)
          | (idxTop[tid * 3 + 2] == row);
    unsigned long long bm = __ballot(f);
    int lane = tid & 63, wv6 = tid >> 6;
    int rank = __popcll(bm & ((1ULL << lane) - 1ULL));
    if (tid < 256 && lane == 0) pfxw[wv6] = __popcll(bm);
    __syncthreads();
    {
        int base = 0;
#pragma unroll
        for (int w = 0; w < 4; w++) base += (w < wv6) ? pfxw[w] : 0;
        if (tid < 256 && f) {
            lst[base + rank] = tid;
            inlist[row * MAXDEG + base + rank] = tid;
        }
    }
    if (tid == 0) {
        int tot = pfxw[0] + pfxw[1] + pfxw[2] + pfxw[3];
        lst[tot] = row;                   // GATConv self loop
        inlist[row * MAXDEG + tot] = row;
        dgS = tot + 1;
        deg[row] = tot + 1;
    }
    __syncthreads();
    int dg = dgS;
    for (int p = tid; p < dg * 4; p += 512) {
        int e = p >> 2, hq2 = p & 3;
        int s = lst[e];
        float v = es1[s * 4 + hq2] + ed1[row * 4 + hq2];
        sc[p] = v >= 0.f ? v : 0.2f * v;  // leaky_relu(0.2)
    }
    __syncthreads();
    int hq = tid & 3;
    {
        float lm = -1e30f;
        for (int e = tid >> 2; e < dg; e += 128)
            lm = fmaxf(lm, sc[e * 4 + hq]);
#pragma unroll
        for (int o = 4; o <= 32; o <<= 1) lm = fmaxf(lm, __shfl_xor(lm, o));
        if (lane < 4) sval[wv6 * 4 + hq] = lm;
        __syncthreads();
        float m = sval[hq];
#pragma unroll
        for (int w = 1; w < 8; w++) m = fmaxf(m, sval[w * 4 + hq]);
        float ls = 0.f;
        for (int e = tid >> 2; e < dg; e += 128) {
            float pv = expf(sc[e * 4 + hq] - m);
            sc[e * 4 + hq] = pv;
            ls += pv;
        }
#pragma unroll
        for (int o = 4; o <= 32; o <<= 1) ls += __shfl_xor(ls, o);
        if (lane < 4) sval[32 + wv6 * 4 + hq] = ls;
        __syncthreads();
        float den = sval[32 + hq];
#pragma unroll
        for (int w = 1; w < 8; w++) den += sval[32 + w * 4 + hq];
        for (int e = tid >> 2; e < dg; e += 128)
            sc[e * 4 + hq] = sc[e * 4 + hq] / den;   // alpha
    }
    __syncthreads();
    {
        int col = tid & 255, hh = (tid >> 8) * 2;   // heads {hh, hh+1}
        float acc0 = 0.f, acc1 = 0.f;
        int e = 0;
        for (; e + 8 <= dg; e += 8) {
            float v0[8], v1[8];
#pragma unroll
            for (int u = 0; u < 8; u++) {
                const float* hs = hpre + (size_t)lst[e + u] * M1;
                v0[u] = hs[hh * GCNH + col];
                v1[u] = hs[(hh + 1) * GCNH + col];
            }
#pragma unroll
            for (int u = 0; u < 8; u++) {
                acc0 = fmaf(sc[(e + u) * 4 + hh],     v0[u], acc0);
                acc1 = fmaf(sc[(e + u) * 4 + hh + 1], v1[u], acc1);
            }
        }
        for (; e < dg; e++) {
            const float* hs = hpre + (size_t)lst[e] * M1;
            acc0 = fmaf(sc[e * 4 + hh],     hs[hh * GCNH + col],       acc0);
            acc1 = fmaf(sc[e * 4 + hh + 1], hs[(hh + 1) * GCNH + col], acc1);
        }
        int c0 = hh * GCNH + col, c1 = (hh + 1) * GCNH + col;
        sh[c0] = fmaxf(acc0 + b1[c0], 0.f);
        sh[c1] = fmaxf(acc1 + b1[c1], 0.f);
    }
    __syncthreads();
    if (tid < 504) {                      // 24-way split of 1024 -> 21
        int o = tid % OUTC, pq = tid / OUTC;
        float a2 = 0.f;
        for (int d = pq; d < M1; d += 24)
            a2 = fmaf(sh[d], W2[d * OUTC + o], a2);
        part[pq * OUTC + o] = a2;
    }
    __syncthreads();
    if (tid < OUTC) {
        float ssum = 0.f;
        for (int pq = 0; pq < 24; pq++) ssum += part[pq * OUTC + tid];
        h2[row * OUTC + tid] = ssum;
        h2row[tid] = ssum;
    }
    __syncthreads();
    if (tid == 0) {
        float ssum = 0.f, dd = 0.f;
        for (int k = 0; k < OUTC; k++) {
            ssum = fmaf(h2row[k], as2[k], ssum);
            dd = fmaf(h2row[k], ad2[k], dd);
        }
        es2[row] = ssum;
        ed2[row] = dd;
    }
}

// ---------------------------------------------------------------------------
// Stage D: GAT-2 softmax-aggregate -> logits + argmax. grid 256 x 512.
__global__ __launch_bounds__(512) void k_stD(
        const int* __restrict__ deg, const int* __restrict__ inlist,
        const float* __restrict__ es2, const float* __restrict__ ed2,
        const float* __restrict__ h2, const float* __restrict__ b2,
        float* __restrict__ out) {
    __shared__ float sval[512];
    __shared__ int lst[MAXDEG];
    __shared__ float scD[MAXDEG];
    __shared__ float part[24 * OUTC];
    __shared__ float lv[OUTC];
    int row = blockIdx.x, tid = threadIdx.x;
    int lane = tid & 63, wv6 = tid >> 6;
    int dgT = deg[row];
    float edt = ed2[row];
    for (int p = tid; p < dgT; p += 512) {
        int s = inlist[row * MAXDEG + p];
        lst[p] = s;
        float v = es2[s] + edt;
        scD[p] = v >= 0.f ? v : 0.2f * v;
    }
    __syncthreads();
    {
        float lm = -1e30f;
        for (int p = tid; p < dgT; p += 512) lm = fmaxf(lm, scD[p]);
#pragma unroll
        for (int o = 1; o <= 32; o <<= 1) lm = fmaxf(lm, __shfl_xor(lm, o));
        if (lane == 0) sval[wv6] = lm;
        __syncthreads();
        float m = sval[0];
#pragma unroll
        for (int w = 1; w < 8; w++) m = fmaxf(m, sval[w]);
        float ls = 0.f;
        for (int p = tid; p < dgT; p += 512) {
            float pv = expf(scD[p] - m);
            scD[p] = pv;
            ls += pv;
        }
#pragma unroll
        for (int o = 1; o <= 32; o <<= 1) ls += __shfl_xor(ls, o);
        if (lane == 0) sval[8 + wv6] = ls;
        __syncthreads();
        float den = sval[8];
#pragma unroll
        for (int w = 1; w < 8; w++) den += sval[8 + w];
        __syncthreads();
        if (tid < 504) {                  // (edge-group, out-channel) map
            int o = tid % OUTC, eg = tid / OUTC;
            float acc = 0.f;
            for (int e = eg; e < dgT; e += 24) {
                int s = lst[e];
                acc = fmaf(scD[e], h2[(size_t)s * OUTC + o], acc);
            }
            part[eg * OUTC + o] = acc;
        }
        __syncthreads();
        if (tid < OUTC) {
            float ssum = 0.f;
            for (int eg = 0; eg < 24; eg++) ssum += part[eg * OUTC + tid];
            float v = ssum / den + b2[tid];
            out[row * OUTC + tid] = v;
            lv[tid] = v;
        }
    }
    __syncthreads();
    if (tid == 0) {
        int best = 0;
        float bv = lv[0];
        for (int o = 1; o < OUTC; o++)
            if (lv[o] > bv) { bv = lv[o]; best = o; }  // first max wins
        out[NN * OUTC + row] = (float)best;
    }
}

// ---------------------------------------------------------------------------
extern "C" void kernel_launch(void* const* d_in, const int* in_sizes, int n_in,
                              void* d_out, int out_size, void* d_ws,
                              size_t ws_size, hipStream_t stream) {
    const float* feat  = (const float*)d_in[0];
    const float* boxes = (const float*)d_in[1];
    const float* Wfc1  = (const float*)d_in[2];
    const float* bfc1  = (const float*)d_in[3];
    const float* Wfc2  = (const float*)d_in[4];
    const float* bfc2  = (const float*)d_in[5];   (void)bfc2;
    const float* W1    = (const float*)d_in[6];
    const float* as1   = (const float*)d_in[7];
    const float* ad1   = (const float*)d_in[8];
    const float* b1    = (const float*)d_in[9];
    const float* W2    = (const float*)d_in[10];
    const float* as2   = (const float*)d_in[11];
    const float* ad2   = (const float*)d_in[12];
    const float* b2    = (const float*)d_in[13];
    const int*   imh   = (const int*)d_in[14];
    const int*   imw   = (const int*)d_in[15];

    float* ws = (float*)d_ws;
    float* P     = ws;  ws += KC * NN * FCOLS;   // 25 MB
    float* A     = ws;  ws += NN * HIDR;
    float* BT4   = ws;  ws += NN * HIDR;
    float* hpre  = ws;  ws += NN * M1;
    float* es1   = ws;  ws += NN * 4;
    float* ed1   = ws;  ws += NN * 4;
    float* h2    = ws;  ws += NN * OUTC;
    float* es2   = ws;  ws += NN;
    float* ed2   = ws;  ws += NN;
    int* idxTop  = (int*)ws;
    int* deg     = idxTop + NN * 3;
    int* inlist  = deg + NN;

    float* out = (float*)d_out;

    k_big<<<768, 256, 0, stream>>>(feat, Wfc1, W1, P);
    k_stA<<<NN, 384, 0, stream>>>(P, bfc1, boxes, imh, imw, W1, as1, ad1,
                                  A, BT4, hpre, es1, ed1);
    k_stB<<<NN, 512, 0, stream>>>(A, boxes, Wfc1, Wfc2, BT4, idxTop);
    k_stC<<<NN, 512, 0, stream>>>(idxTop, es1, ed1, hpre, b1, W2, as2, ad2,
                                  deg, inlist, h2, es2, ed2);
    k_stD<<<NN, 512, 0, stream>>>(deg, inlist, es2, ed2, h2, b2, out);
}